// Round 9
// baseline (228.914 us; speedup 1.0000x reference)
//
#include <hip/hip_runtime.h>
#include <hip/hip_bf16.h>
#include <cstddef>

typedef __attribute__((ext_vector_type(8))) short s8v;
typedef __attribute__((ext_vector_type(4))) float f32x4;

// ---------------- weight fusion kernels ----------------
// Merged small repacks: W34 (288), w1b (24576), w8b (7168)
__global__ void fuse_small(const float* __restrict__ w3, const float* __restrict__ w4,
                           const float* __restrict__ w1, const float* __restrict__ w8,
                           float* __restrict__ W34, __hip_bfloat16* __restrict__ w1b,
                           __hip_bfloat16* __restrict__ w8b) {
    int idx = blockIdx.x * blockDim.x + threadIdx.x;
    if (idx < 288) {
        int ci = idx / 9, k1 = (idx / 3) % 3, k2 = idx % 3;
        float s = 0.f;
        for (int co = 0; co < 256; ++co)
            s += w3[(co * 32 + ci) * 3 + k1] * w4[co * 3 + k2];
        W34[idx] = s;
    }
    int i1 = idx - 512;
    if (i1 >= 0 && i1 < 24576) {
        int j = i1 & 7, co = (i1 >> 3) & 31, h = (i1 >> 8) & 3, c = (i1 >> 10) & 7, k = i1 >> 13;
        int ci = c * 32 + h * 8 + j;
        w1b[i1] = __float2bfloat16(w1[(co * 256 + ci) * 3 + k]);
    }
    int i2 = idx - 25600;
    if (i2 >= 0 && i2 < 7168) {
        int jj = i2 & 7, co = (i2 >> 3) & 31, h = (i2 >> 8) & 3, j = i2 >> 10;
        w8b[i2] = __float2bfloat16(w8[co * 224 + (h * 8 + jj) * 7 + j]);
    }
}

// Wfb[kk][co][ci] (bf16), kk = dy*7+dx:  sum_m w15[o,3m+dy] * w12[m,ci,dx]
__global__ void fuse_w1215b(const float* __restrict__ w15, const float* __restrict__ w12,
                            __hip_bfloat16* __restrict__ Wfb) {
    int idx = blockIdx.x * blockDim.x + threadIdx.x;
    if (idx >= 21 * 256 * 32) return;
    int ci = idx & 31, co = (idx >> 5) & 255, kk = idx >> 13;
    int dy = kk / 7, dx = kk % 7;
    float s = 0.f;
#pragma unroll 8
    for (int m = 0; m < 256; ++m)
        s += w15[co * 768 + m * 3 + dy] * w12[(m * 32 + ci) * 7 + dx];
    Wfb[idx] = __float2bfloat16(s);
}

// ---------------- t1 fused MFMA: conv 256->32, 3 w-taps dil 3 ----------------
// grid 1792 (n,y), block 256 = 4 waves. Coalesced float4 x-reads (ci pairs) ->
// packed b32 LDS writes into transpose tile [70 pos][32 g(8ci)], slot = g ^ (pos&15).
__global__ __launch_bounds__(256) void k_t1f(const float* __restrict__ x,
                                             const unsigned short* __restrict__ w1b,
                                             float* __restrict__ t1) {
    __shared__ __align__(16) char lds[36864];
    const int t = threadIdx.x, b = blockIdx.x;
    const int n = b / 56, y = b % 56;
    const int w = t >> 6, l = t & 63, h = l >> 4, q = l & 15;
    const float* xr = x + (size_t)(n * 256) * 3136 + y * 56;  // + ci*3136 + xx

    // ---- halo zeros: pos {0,1,2,59..69} x 32 g = 448 units ----
#pragma unroll
    for (int it = 0; it < 2; ++it) {
        int u = it * 256 + t;
        if (u < 448) {
            int pi = u >> 5, g = u & 31;
            int pos = (pi < 3) ? pi : (56 + pi);
            *reinterpret_cast<s8v*>(lds + pos * 512 + ((g ^ (pos & 15)) << 4)) = (s8v)0;
        }
    }
    // ---- coalesced stage: 1792 units (ci-pair, xq), packed b32 LDS writes ----
#pragma unroll 2
    for (int it = 0; it < 7; ++it) {
        int u = it * 256 + t;
        int c2 = u / 14, xq = u % 14;
        int ci = c2 * 2;
        float4 a = *(const float4*)(xr + (size_t)ci * 3136 + xq * 4);
        float4 bv = *(const float4*)(xr + (size_t)(ci + 1) * 3136 + xq * 4);
        int g = ci >> 3, lo = (ci & 7) * 2;
#pragma unroll
        for (int j = 0; j < 4; ++j) {
            int pos = xq * 4 + j + 3;
            __hip_bfloat16 b0 = __float2bfloat16(((const float*)&a)[j]);
            __hip_bfloat16 b1 = __float2bfloat16(((const float*)&bv)[j]);
            unsigned int wd = (unsigned int)(*(unsigned short*)&b0) |
                              ((unsigned int)(*(unsigned short*)&b1) << 16);
            *(unsigned int*)(lds + pos * 512 + ((g ^ (pos & 15)) << 4) + lo) = wd;
        }
    }
    __syncthreads();

    f32x4 acc[2][4];
#pragma unroll
    for (int m = 0; m < 2; ++m)
#pragma unroll
        for (int nt = 0; nt < 4; ++nt) acc[m][nt] = (f32x4)0.f;

    // ---- K-loop: wave w handles ci-chunks {2w, 2w+1}; no barriers ----
    for (int cc = 0; cc < 2; ++cc) {
        const int c = 2 * w + cc;
        const int g = c * 4 + h;
#pragma unroll
        for (int k = 0; k < 3; ++k) {
            s8v af[2];
#pragma unroll
            for (int m = 0; m < 2; ++m)
                af[m] = *reinterpret_cast<const s8v*>(
                    w1b + (size_t)((((k * 8 + c) * 4 + h) * 32 + m * 16 + q) * 8));
#pragma unroll
            for (int nt = 0; nt < 4; ++nt) {
                int pos = nt * 16 + q + 3 * k;
                s8v bf = *reinterpret_cast<const s8v*>(lds + pos * 512 + ((g ^ (pos & 15)) << 4));
                acc[0][nt] = __builtin_amdgcn_mfma_f32_16x16x32_bf16(af[0], bf, acc[0][nt], 0, 0, 0);
                acc[1][nt] = __builtin_amdgcn_mfma_f32_16x16x32_bf16(af[1], bf, acc[1][nt], 0, 0, 0);
            }
        }
    }

    // ---- reduce 4 partial K-sums via LDS, wave 0 stores ----
    __syncthreads();
    if (w > 0) {
#pragma unroll
        for (int m = 0; m < 2; ++m)
#pragma unroll
            for (int nt = 0; nt < 4; ++nt)
                *reinterpret_cast<f32x4*>(lds + (((w - 1) * 8 + m * 4 + nt) * 64 + l) * 16) =
                    acc[m][nt];
    }
    __syncthreads();
    if (w == 0) {
#pragma unroll
        for (int m = 0; m < 2; ++m)
#pragma unroll
            for (int nt = 0; nt < 4; ++nt) {
                f32x4 a = acc[m][nt];
#pragma unroll
                for (int s = 0; s < 3; ++s)
                    a += *reinterpret_cast<const f32x4*>(
                        lds + ((s * 8 + m * 4 + nt) * 64 + l) * 16);
                int px = nt * 16 + q;
                if (px < 56) {
#pragma unroll
                    for (int r = 0; r < 4; ++r)
                        t1[((size_t)(n * 32 + m * 16 + h * 4 + r) * 56 + y) * 56 + px] = a[r];
                }
            }
    }
}

// ---------------- t4: 32ch, 3x3 taps dil (2,3), via W34 (4 rows/block) ----------------
__global__ __launch_bounds__(256) void k_t4(const float* __restrict__ t1,
                                            const float* __restrict__ W34,
                                            float* __restrict__ t4) {
    int by = blockIdx.x;  // 448
    int n = by / 14;
    int y = (by % 14) * 4 + (threadIdx.x >> 6);
    int px = threadIdx.x & 63;
    if (px >= 56) return;
    float acc = 0.f;
#pragma unroll 4
    for (int ci = 0; ci < 32; ++ci) {
#pragma unroll
        for (int k1 = 0; k1 < 3; ++k1) {
            int yy = y + 2 * k1 - 2;
            if (yy < 0 || yy >= 56) continue;
            const float* r = t1 + ((size_t)(n * 32 + ci) * 56 + yy) * 56;
#pragma unroll
            for (int k2 = 0; k2 < 3; ++k2) {
                int xx = px + 3 * k2 - 3;
                if (xx >= 0 && xx < 56)
                    acc += r[xx] * W34[ci * 9 + k1 * 3 + k2];
            }
        }
    }
    t4[(size_t)(n * 56 + y) * 56 + px] = acc;
}

// ---------------- pool: t4 -> t11, two-pass colmax via LDS (4-row slabs) ----------------
// R(yc,xx) = relu(max_i t4[yc+3i-9, xx]) staged for yc in [y0-1, y0+4];
// t11(y,px) = sum_{dy,j} R terms / 21.  336 stage units on 256 threads -> strided loop.
__global__ __launch_bounds__(256) void k_pool(const float* __restrict__ t4,
                                              float* __restrict__ t11) {
    __shared__ float R[6][64];
    int b = blockIdx.x;  // 448
    int n = b / 14, y0 = (b % 14) * 4;
    int t = threadIdx.x;
    for (int e = t; e < 336; e += 256) {
        int ridx = e / 56, xx = e % 56;
        int yc = y0 - 1 + ridx;
        float rv = 0.f;
        if (yc >= 0 && yc < 56) {
            float mm = -3.4e38f;
#pragma unroll
            for (int i = 0; i < 7; ++i) {
                int yy = yc + 3 * i - 9;
                float v = (yy >= 0 && yy < 56) ? t4[(size_t)(n * 56 + yy) * 56 + xx] : 0.f;
                mm = fmaxf(mm, v);
            }
            rv = fmaxf(mm, 0.f);
        }
        R[ridx][xx] = rv;
    }
    __syncthreads();
    if (t < 224) {
        int yi = t / 56, px = t % 56;
        int y = y0 + yi;
        float s = 0.f;
#pragma unroll
        for (int dy = 0; dy < 3; ++dy) {
            int yreal = y + dy - 1;
            if (yreal < 0 || yreal >= 56) continue;
            int row = yi + dy;
#pragma unroll
            for (int j = 0; j < 7; ++j) {
                int xx = px + 3 * j - 9;
                if (xx >= 0 && xx < 56) s += R[row][xx];
            }
        }
        t11[(size_t)(n * 56 + y) * 56 + px] = s * (1.f / 21.f);
    }
}

// ---------------- t14: 3x3 conv on t11 (4 rows/block) ----------------
__global__ __launch_bounds__(256) void k_t14(const float* __restrict__ t11,
                                             const float* __restrict__ w14,
                                             float* __restrict__ t14) {
    int by = blockIdx.x;  // 448
    int n = by / 14;
    int y = (by % 14) * 4 + (threadIdx.x >> 6);
    int px = threadIdx.x & 63;
    if (px >= 56) return;
    float s = 0.f;
#pragma unroll
    for (int dy = 0; dy < 3; ++dy) {
        int yy = y + dy - 1;
        if (yy < 0 || yy >= 56) continue;
#pragma unroll
        for (int dx = 0; dx < 3; ++dx) {
            int xx = px + dx - 1;
            if (xx < 0 || xx >= 56) continue;
            s += t11[(size_t)(n * 56 + yy) * 56 + xx] * w14[dy * 3 + dx];
        }
    }
    t14[(size_t)(n * 56 + y) * 56 + px] = s;
}

// ---------------- fused t5+t8 MFMA -> t8T (LDS rowbuf, coalesced stores) ----------------
__global__ __launch_bounds__(256) void k_t58(const float* __restrict__ t1,
                                             const float* __restrict__ p2w,
                                             const float* __restrict__ w5,
                                             const unsigned short* __restrict__ w8b,
                                             char* __restrict__ t8T) {
    __shared__ __align__(16) char lds[9344];  // [0,4864) stage, [4864,9344) rowbuf
    const int t = threadIdx.x, b = blockIdx.x;
    const int n = b / 56, y = b % 56;
    const int w = t >> 6, l = t & 63, h = l >> 4, q = l & 15;
    const float* t1b = t1 + (size_t)(n * 32) * 3136;
    char* rowbuf = lds + 4864;

    // stage halo zeros: pos {0..5, 62..75} x 4 g = 80 units
    if (t < 80) {
        int ph = t >> 2, g = t & 3;
        int pos = (ph < 6) ? ph : (56 + ph);
        *reinterpret_cast<s8v*>(lds + pos * 64 + ((g ^ ((pos >> 1) & 3)) << 4)) = (s8v)0;
    }
    // rowbuf halo zeros: pos {0,1,2,59..69} x 4 = 56 units
    if (t >= 80 && t < 136) {
        int u = t - 80;
        int ph = u >> 2, g = u & 3;
        int pos = (ph < 3) ? ph : (56 + ph);
        *reinterpret_cast<s8v*>(rowbuf + pos * 64 + ((g ^ ((pos >> 1) & 3)) << 4)) = (s8v)0;
    }
    // stage: 448 units (ci, xq); t5 = p2w[ci] * sum_k w5[ci,k] * t1[ci, y+3k-3, :]
#pragma unroll
    for (int it = 0; it < 2; ++it) {
        int u = it * 256 + t;
        if (u < 448) {
            int ci = u / 14, xq = u % 14;
            float sc = p2w[ci];
            float4 s = {0.f, 0.f, 0.f, 0.f};
#pragma unroll
            for (int k = 0; k < 3; ++k) {
                int yy = y + 3 * k - 3;
                if (yy < 0 || yy >= 56) continue;
                float wv = w5[ci * 3 + k] * sc;
                float4 v = *(const float4*)(t1b + (size_t)ci * 3136 + yy * 56 + xq * 4);
                s.x += wv * v.x; s.y += wv * v.y; s.z += wv * v.z; s.w += wv * v.w;
            }
            int g = ci >> 3, lo = (ci & 7) * 2;
#pragma unroll
            for (int j = 0; j < 4; ++j) {
                int pos = xq * 4 + j + 6;
                __hip_bfloat16 bv = __float2bfloat16(((const float*)&s)[j]);
                *(unsigned short*)(lds + pos * 64 + ((g ^ ((pos >> 1) & 3)) << 4) + lo) =
                    *(unsigned short*)&bv;
            }
        }
    }
    __syncthreads();

    f32x4 acc[2];
    acc[0] = (f32x4)0.f; acc[1] = (f32x4)0.f;
#pragma unroll
    for (int j = 0; j < 7; ++j) {
        s8v af[2];
#pragma unroll
        for (int m = 0; m < 2; ++m)
            af[m] = *reinterpret_cast<const s8v*>(
                w8b + (size_t)(((j * 4 + h) * 32 + m * 16 + q) * 8));
        int pos = w * 16 + q + 2 * j;
        s8v bf = *reinterpret_cast<const s8v*>(lds + pos * 64 + ((h ^ ((pos >> 1) & 3)) << 4));
        acc[0] = __builtin_amdgcn_mfma_f32_16x16x32_bf16(af[0], bf, acc[0], 0, 0, 0);
        acc[1] = __builtin_amdgcn_mfma_f32_16x16x32_bf16(af[1], bf, acc[1], 0, 0, 0);
    }

    // scatter D-frags to LDS rowbuf (pos = x+3, slot = g ^ ((pos>>1)&3))
    int xx = w * 16 + q;
    if (xx < 56) {
        int pos = xx + 3;
#pragma unroll
        for (int m = 0; m < 2; ++m) {
#pragma unroll
            for (int r = 0; r < 4; ++r) {
                int co = m * 16 + h * 4 + r;
                __hip_bfloat16 bv = __float2bfloat16(acc[m][r]);
                *(unsigned short*)(rowbuf + pos * 64 + (((co >> 3) ^ ((pos >> 1) & 3)) << 4) +
                                   (co & 7) * 2) = *(unsigned short*)&bv;
            }
        }
    }
    __syncthreads();
    // coalesced copy rowbuf -> t8T row (280 x 16B)
    char* rowo = t8T + (size_t)(n * 56 + y) * 4480;
    for (int u = t; u < 280; u += 256)
        *reinterpret_cast<s8v*>(rowo + u * 16) = *reinterpret_cast<const s8v*>(rowbuf + u * 16);
}

// ---------------- MFMA fused kernel: t8T -> t15 -> t16 + t14 -> out ----------------
// grid 1792 = 32 n x 28 ypair x 2 co-half; block 256 = 4 waves: wave w ->
// (row rg = w>>1, co quadrant = coh*2 + (w&1)). Stage 6 t8T rows (26.9 KB);
// contiguous kk K-loop with 1-deep A prefetch; shuffle epilogue; NT stores.
__global__ __launch_bounds__(256) void k_t15m5(const char* __restrict__ t8T,
                                               const unsigned short* __restrict__ Wfb,
                                               const float* __restrict__ w16,
                                               const float* __restrict__ t14,
                                               float* __restrict__ out) {
    __shared__ __align__(16) char lds[26880];
    const int t = threadIdx.x;
    const int b = blockIdx.x;
    const int n = b / 56;
    const int rr = b % 56;
    const int yp = rr >> 1, coh = rr & 1;
    const int y0 = yp * 2;
    const int l = t & 63, h = l >> 4, q = l & 15;
    const int w = t >> 6, rg = w >> 1;
    const int y = y0 + rg;
    const int co0 = coh * 128 + (w & 1) * 64;

    // ---- stage 6 t8T rows y0-2 .. y0+3 (linear 16B copies) ----
    for (int e = t; e < 1680; e += 256) {
        int ridx = e / 280, u = e - ridx * 280;
        int yy = y0 - 2 + ridx;
        if (yy >= 0 && yy < 56)
            *reinterpret_cast<s8v*>(lds + ridx * 4480 + u * 16) =
                *reinterpret_cast<const s8v*>(t8T + (size_t)(n * 56 + yy) * 4480 + u * 16);
    }
    __syncthreads();

    f32x4 acc[4][4];
#pragma unroll
    for (int m = 0; m < 4; ++m)
#pragma unroll
        for (int nt = 0; nt < 4; ++nt)
            acc[m][nt] = (f32x4)0.f;

    // valid dy are contiguous: kk in [kklo, kkhi)
    const int kklo = (y >= 2) ? 0 : 7;
    const int kkhi = (y <= 53) ? 21 : 14;

    s8v af[4];
#pragma unroll
    for (int m = 0; m < 4; ++m)
        af[m] = *reinterpret_cast<const s8v*>(
            Wfb + (size_t)kklo * 8192 + (co0 + m * 16 + q) * 32 + h * 8);

    for (int kk = kklo; kk < kkhi; ++kk) {
        const int dy = kk / 7, dx = kk - dy * 7;
        const char* bbase = lds + (rg + 2 * dy) * 4480;
        s8v bf[4];
#pragma unroll
        for (int nt = 0; nt < 4; ++nt) {
            int xp = nt * 16 + q + dx;
            bf[nt] = *reinterpret_cast<const s8v*>(bbase + xp * 64 + ((h ^ ((xp >> 1) & 3)) << 4));
        }
        s8v afn[4];
        if (kk + 1 < kkhi) {
#pragma unroll
            for (int m = 0; m < 4; ++m)
                afn[m] = *reinterpret_cast<const s8v*>(
                    Wfb + (size_t)(kk + 1) * 8192 + (co0 + m * 16 + q) * 32 + h * 8);
        }
#pragma unroll
        for (int nt = 0; nt < 4; ++nt)
#pragma unroll
            for (int m = 0; m < 4; ++m)
                acc[m][nt] = __builtin_amdgcn_mfma_f32_16x16x32_bf16(af[m], bf[nt], acc[m][nt], 0, 0, 0);
#pragma unroll
        for (int m = 0; m < 4; ++m) af[m] = afn[m];
    }

    // ---- t16 + t14 epilogue: in-register x+-3 via shuffles, NT f32 stores ----
    const float* t14r = t14 + (size_t)(n * 56 + y) * 56;
    float t14v[4];
#pragma unroll
    for (int nt = 0; nt < 4; ++nt) {
        int xx = nt * 16 + q;
        t14v[nt] = (xx < 56) ? t14r[xx] : 0.f;
    }
    const int srcm = (l & 48) | ((q + 13) & 15);
    const int srcp = (l & 48) | ((q + 3) & 15);
#pragma unroll
    for (int m = 0; m < 4; ++m) {
#pragma unroll
        for (int r = 0; r < 4; ++r) {
            int co = co0 + m * 16 + h * 4 + r;
            float wa = w16[co * 3], wb = w16[co * 3 + 1], wc = w16[co * 3 + 2];
            float v[4], rm[4], rp[4];
#pragma unroll
            for (int nt = 0; nt < 4; ++nt) v[nt] = acc[m][nt][r];
#pragma unroll
            for (int nt = 0; nt < 4; ++nt) {
                rm[nt] = __shfl(v[nt], srcm, 64);
                rp[nt] = __shfl(v[nt], srcp, 64);
            }
            float* orow = out + ((size_t)(n * 256 + co) * 56 + y) * 56;
#pragma unroll
            for (int nt = 0; nt < 4; ++nt) {
                int xx = nt * 16 + q;
                float vm = (q >= 3) ? rm[nt] : (nt > 0 ? rm[nt - 1] : 0.f);
                float vp = (q < 13) ? rp[nt] : (nt < 3 ? rp[nt + 1] : 0.f);
                float s = v[nt] * wb + t14v[nt];
                s += (xx >= 3) ? vm * wa : 0.f;
                s += (xx <= 52) ? vp * wc : 0.f;
                if (xx < 56) __builtin_nontemporal_store(s, orow + xx);
            }
        }
    }
}

extern "C" void kernel_launch(void* const* d_in, const int* in_sizes, int n_in,
                              void* d_out, int out_size, void* d_ws, size_t ws_size,
                              hipStream_t stream) {
    const float* x   = (const float*)d_in[0];
    const float* w1  = (const float*)d_in[1];
    const float* p2w = (const float*)d_in[2];
    const float* w3  = (const float*)d_in[3];
    const float* w4  = (const float*)d_in[4];
    const float* w5  = (const float*)d_in[5];
    const float* w8  = (const float*)d_in[6];
    const float* w12 = (const float*)d_in[7];
    const float* w14 = (const float*)d_in[8];
    const float* w15 = (const float*)d_in[9];
    const float* w16 = (const float*)d_in[10];
    float* out = (float*)d_out;

    float* ws = (float*)d_ws;
    float* t1   = ws;                  // 3211264 f32
    char*  t8T  = (char*)(t1 + 3211264);  // 8,028,160 B
    float* t4   = t1 + 2 * 3211264;    // 100352
    float* t11  = t4 + 100352;         // 100352
    float* t14v = t11 + 100352;        // 100352
    float* W34  = t14v + 100352;       // 288
    __hip_bfloat16* Wfb = (__hip_bfloat16*)(W34 + 288);   // 172032 bf16
    __hip_bfloat16* w1b = Wfb + 172032;                   // 24576 bf16
    __hip_bfloat16* w8b = w1b + 24576;                    // 7168 bf16

    fuse_small<<<128, 256, 0, stream>>>(w3, w4, w1, w8, W34, w1b, w8b);
    fuse_w1215b<<<672, 256, 0, stream>>>(w15, w12, Wfb);

    k_t1f<<<1792, 256, 0, stream>>>(x, (const unsigned short*)w1b, t1);
    k_t4<<<448, 256, 0, stream>>>(t1, W34, t4);
    k_pool<<<448, 256, 0, stream>>>(t4, t11);
    k_t14<<<448, 256, 0, stream>>>(t11, w14, t14v);
    k_t58<<<1792, 256, 0, stream>>>(t1, p2w, w5, (const unsigned short*)w8b, t8T);
    k_t15m5<<<1792, 256, 0, stream>>>(t8T, (const unsigned short*)Wfb, w16, t14v, out);
}

// Round 10
// 217.163 us; speedup vs baseline: 1.0541x; 1.0541x over previous
//
#include <hip/hip_runtime.h>
#include <hip/hip_bf16.h>
#include <cstddef>

typedef __attribute__((ext_vector_type(8))) short s8v;
typedef __attribute__((ext_vector_type(4))) float f32x4;

// ---------------- weight fusion kernels ----------------
// Merged small repacks: W34 (288), w1b (24576), w8b (7168)
__global__ void fuse_small(const float* __restrict__ w3, const float* __restrict__ w4,
                           const float* __restrict__ w1, const float* __restrict__ w8,
                           float* __restrict__ W34, __hip_bfloat16* __restrict__ w1b,
                           __hip_bfloat16* __restrict__ w8b) {
    int idx = blockIdx.x * blockDim.x + threadIdx.x;
    if (idx < 288) {
        int ci = idx / 9, k1 = (idx / 3) % 3, k2 = idx % 3;
        float s = 0.f;
        for (int co = 0; co < 256; ++co)
            s += w3[(co * 32 + ci) * 3 + k1] * w4[co * 3 + k2];
        W34[idx] = s;
    }
    int i1 = idx - 512;
    if (i1 >= 0 && i1 < 24576) {
        int j = i1 & 7, co = (i1 >> 3) & 31, h = (i1 >> 8) & 3, c = (i1 >> 10) & 7, k = i1 >> 13;
        int ci = c * 32 + h * 8 + j;
        w1b[i1] = __float2bfloat16(w1[(co * 256 + ci) * 3 + k]);
    }
    int i2 = idx - 25600;
    if (i2 >= 0 && i2 < 7168) {
        int jj = i2 & 7, co = (i2 >> 3) & 31, h = (i2 >> 8) & 3, j = i2 >> 10;
        w8b[i2] = __float2bfloat16(w8[co * 224 + (h * 8 + jj) * 7 + j]);
    }
}

// Wfb[kk][co][ci] (bf16), kk = dy*7+dx:  sum_m w15[o,3m+dy] * w12[m,ci,dx]
__global__ void fuse_w1215b(const float* __restrict__ w15, const float* __restrict__ w12,
                            __hip_bfloat16* __restrict__ Wfb) {
    int idx = blockIdx.x * blockDim.x + threadIdx.x;
    if (idx >= 21 * 256 * 32) return;
    int ci = idx & 31, co = (idx >> 5) & 255, kk = idx >> 13;
    int dy = kk / 7, dx = kk % 7;
    float s = 0.f;
#pragma unroll 8
    for (int m = 0; m < 256; ++m)
        s += w15[co * 768 + m * 3 + dy] * w12[(m * 32 + ci) * 7 + dx];
    Wfb[idx] = __float2bfloat16(s);
}

// ---------------- t1 fused MFMA: conv 256->32, 3 w-taps dil 3 ----------------
// grid 1792 (n,y), block 256 = 4 waves. Wave w owns px quarter [16w,16w+16),
// runs FULL K (8 ci-chunks x 3 taps) -> no reduce, no post-loop barriers,
// parallel stores. Stage: coalesced float4 ci-pair reads -> packed b32 LDS
// writes, transpose tile [70 pos][32 g(8ci)], slot = g ^ (pos&15).
__global__ __launch_bounds__(256) void k_t1f(const float* __restrict__ x,
                                             const unsigned short* __restrict__ w1b,
                                             float* __restrict__ t1) {
    __shared__ __align__(16) char lds[35840];
    const int t = threadIdx.x, b = blockIdx.x;
    const int n = b / 56, y = b % 56;
    const int w = t >> 6, l = t & 63, h = l >> 4, q = l & 15;
    const float* xr = x + (size_t)(n * 256) * 3136 + y * 56;  // + ci*3136 + xx

    // ---- halo zeros: pos {0,1,2,59..69} x 32 g = 448 units ----
#pragma unroll
    for (int it = 0; it < 2; ++it) {
        int u = it * 256 + t;
        if (u < 448) {
            int pi = u >> 5, g = u & 31;
            int pos = (pi < 3) ? pi : (56 + pi);
            *reinterpret_cast<s8v*>(lds + pos * 512 + ((g ^ (pos & 15)) << 4)) = (s8v)0;
        }
    }
    // ---- coalesced stage: 1792 units (ci-pair, xq), packed b32 LDS writes ----
#pragma unroll 2
    for (int it = 0; it < 7; ++it) {
        int u = it * 256 + t;
        int c2 = u / 14, xq = u % 14;
        int ci = c2 * 2;
        float4 a = *(const float4*)(xr + (size_t)ci * 3136 + xq * 4);
        float4 bv = *(const float4*)(xr + (size_t)(ci + 1) * 3136 + xq * 4);
        int g = ci >> 3, lo = (ci & 7) * 2;
#pragma unroll
        for (int j = 0; j < 4; ++j) {
            int pos = xq * 4 + j + 3;
            __hip_bfloat16 b0 = __float2bfloat16(((const float*)&a)[j]);
            __hip_bfloat16 b1 = __float2bfloat16(((const float*)&bv)[j]);
            unsigned int wd = (unsigned int)(*(unsigned short*)&b0) |
                              ((unsigned int)(*(unsigned short*)&b1) << 16);
            *(unsigned int*)(lds + pos * 512 + ((g ^ (pos & 15)) << 4) + lo) = wd;
        }
    }
    __syncthreads();

    f32x4 acc[2];
    acc[0] = (f32x4)0.f;
    acc[1] = (f32x4)0.f;

    // ---- full-K loop per wave; barrier-free ----
    for (int c = 0; c < 8; ++c) {
        const int g = c * 4 + h;
#pragma unroll
        for (int k = 0; k < 3; ++k) {
            s8v af[2];
#pragma unroll
            for (int m = 0; m < 2; ++m)
                af[m] = *reinterpret_cast<const s8v*>(
                    w1b + (size_t)((((k * 8 + c) * 4 + h) * 32 + m * 16 + q) * 8));
            int pos = w * 16 + q + 3 * k;
            s8v bf = *reinterpret_cast<const s8v*>(lds + pos * 512 + ((g ^ (pos & 15)) << 4));
            acc[0] = __builtin_amdgcn_mfma_f32_16x16x32_bf16(af[0], bf, acc[0], 0, 0, 0);
            acc[1] = __builtin_amdgcn_mfma_f32_16x16x32_bf16(af[1], bf, acc[1], 0, 0, 0);
        }
    }

    int px = w * 16 + q;
    if (px < 56) {
#pragma unroll
        for (int m = 0; m < 2; ++m)
#pragma unroll
            for (int r = 0; r < 4; ++r)
                t1[((size_t)(n * 32 + m * 16 + h * 4 + r) * 56 + y) * 56 + px] = acc[m][r];
    }
}

// ---------------- t4: 32ch, 3x3 taps dil (2,3), via W34 (4 rows/block) ----------------
__global__ __launch_bounds__(256) void k_t4(const float* __restrict__ t1,
                                            const float* __restrict__ W34,
                                            float* __restrict__ t4) {
    int by = blockIdx.x;  // 448
    int n = by / 14;
    int y = (by % 14) * 4 + (threadIdx.x >> 6);
    int px = threadIdx.x & 63;
    if (px >= 56) return;
    float acc = 0.f;
#pragma unroll 4
    for (int ci = 0; ci < 32; ++ci) {
#pragma unroll
        for (int k1 = 0; k1 < 3; ++k1) {
            int yy = y + 2 * k1 - 2;
            if (yy < 0 || yy >= 56) continue;
            const float* r = t1 + ((size_t)(n * 32 + ci) * 56 + yy) * 56;
#pragma unroll
            for (int k2 = 0; k2 < 3; ++k2) {
                int xx = px + 3 * k2 - 3;
                if (xx >= 0 && xx < 56)
                    acc += r[xx] * W34[ci * 9 + k1 * 3 + k2];
            }
        }
    }
    t4[(size_t)(n * 56 + y) * 56 + px] = acc;
}

// ---------------- fused pool + t14: t4 -> (t11 in LDS) -> t14 ----------------
// Block = 4-row slab. R[8] = relu(colmax) rows y0-2..y0+5; T[6] = t11 rows
// y0-1..y0+4; out = 3x3 conv rows y0..y0+3. t11 never touches HBM.
__global__ __launch_bounds__(256) void k_pt(const float* __restrict__ t4,
                                            const float* __restrict__ w14,
                                            float* __restrict__ t14o) {
    __shared__ float R[8][64];
    __shared__ float T[6][64];
    int b = blockIdx.x;  // 448
    int n = b / 14, y0 = (b % 14) * 4;
    int t = threadIdx.x;
    // pass 1: R rows yc = y0-2 .. y0+5
    for (int e = t; e < 448; e += 256) {
        int ridx = e / 56, xx = e % 56;
        int yc = y0 - 2 + ridx;
        float rv = 0.f;
        if (yc >= 0 && yc < 56) {
            float mm = -3.4e38f;
#pragma unroll
            for (int i = 0; i < 7; ++i) {
                int yy = yc + 3 * i - 9;
                float v = (yy >= 0 && yy < 56) ? t4[(size_t)(n * 56 + yy) * 56 + xx] : 0.f;
                mm = fmaxf(mm, v);
            }
            rv = fmaxf(mm, 0.f);
        }
        R[ridx][xx] = rv;
    }
    __syncthreads();
    // pass 2: T rows yt = y0-1 .. y0+4 (t11)
    for (int e = t; e < 336; e += 256) {
        int ti = e / 56, px = e % 56;
        int yt = y0 - 1 + ti;
        float s = 0.f;
        if (yt >= 0 && yt < 56) {
#pragma unroll
            for (int dy = 0; dy < 3; ++dy) {
                int yr = yt + dy - 1;
                if (yr < 0 || yr >= 56) continue;
                int row = ti + dy;  // = yr - (y0-2)
#pragma unroll
                for (int j = 0; j < 7; ++j) {
                    int xx = px + 3 * j - 9;
                    if (xx >= 0 && xx < 56) s += R[row][xx];
                }
            }
            s *= (1.f / 21.f);
        }
        T[ti][px] = s;
    }
    __syncthreads();
    // pass 3: t14 rows y0..y0+3
    if (t < 224) {
        int yi = t / 56, px = t % 56;
        int y = y0 + yi;
        float s = 0.f;
#pragma unroll
        for (int dy = 0; dy < 3; ++dy) {
            int yy = y + dy - 1;
            if (yy < 0 || yy >= 56) continue;
            int row = yi + dy;  // = yy - (y0-1)
#pragma unroll
            for (int dx = 0; dx < 3; ++dx) {
                int xx = px + dx - 1;
                if (xx < 0 || xx >= 56) continue;
                s += T[row][xx] * w14[dy * 3 + dx];
            }
        }
        t14o[(size_t)(n * 56 + y) * 56 + px] = s;
    }
}

// ---------------- fused t5+t8 MFMA -> t8T (LDS rowbuf, coalesced stores) ----------------
__global__ __launch_bounds__(256) void k_t58(const float* __restrict__ t1,
                                             const float* __restrict__ p2w,
                                             const float* __restrict__ w5,
                                             const unsigned short* __restrict__ w8b,
                                             char* __restrict__ t8T) {
    __shared__ __align__(16) char lds[9344];  // [0,4864) stage, [4864,9344) rowbuf
    const int t = threadIdx.x, b = blockIdx.x;
    const int n = b / 56, y = b % 56;
    const int w = t >> 6, l = t & 63, h = l >> 4, q = l & 15;
    const float* t1b = t1 + (size_t)(n * 32) * 3136;
    char* rowbuf = lds + 4864;

    // stage halo zeros: pos {0..5, 62..75} x 4 g = 80 units
    if (t < 80) {
        int ph = t >> 2, g = t & 3;
        int pos = (ph < 6) ? ph : (56 + ph);
        *reinterpret_cast<s8v*>(lds + pos * 64 + ((g ^ ((pos >> 1) & 3)) << 4)) = (s8v)0;
    }
    // rowbuf halo zeros: pos {0,1,2,59..69} x 4 = 56 units
    if (t >= 80 && t < 136) {
        int u = t - 80;
        int ph = u >> 2, g = u & 3;
        int pos = (ph < 3) ? ph : (56 + ph);
        *reinterpret_cast<s8v*>(rowbuf + pos * 64 + ((g ^ ((pos >> 1) & 3)) << 4)) = (s8v)0;
    }
    // stage: 448 units (ci, xq); t5 = p2w[ci] * sum_k w5[ci,k] * t1[ci, y+3k-3, :]
#pragma unroll
    for (int it = 0; it < 2; ++it) {
        int u = it * 256 + t;
        if (u < 448) {
            int ci = u / 14, xq = u % 14;
            float sc = p2w[ci];
            float4 s = {0.f, 0.f, 0.f, 0.f};
#pragma unroll
            for (int k = 0; k < 3; ++k) {
                int yy = y + 3 * k - 3;
                if (yy < 0 || yy >= 56) continue;
                float wv = w5[ci * 3 + k] * sc;
                float4 v = *(const float4*)(t1b + (size_t)ci * 3136 + yy * 56 + xq * 4);
                s.x += wv * v.x; s.y += wv * v.y; s.z += wv * v.z; s.w += wv * v.w;
            }
            int g = ci >> 3, lo = (ci & 7) * 2;
#pragma unroll
            for (int j = 0; j < 4; ++j) {
                int pos = xq * 4 + j + 6;
                __hip_bfloat16 bv = __float2bfloat16(((const float*)&s)[j]);
                *(unsigned short*)(lds + pos * 64 + ((g ^ ((pos >> 1) & 3)) << 4) + lo) =
                    *(unsigned short*)&bv;
            }
        }
    }
    __syncthreads();

    f32x4 acc[2];
    acc[0] = (f32x4)0.f; acc[1] = (f32x4)0.f;
#pragma unroll
    for (int j = 0; j < 7; ++j) {
        s8v af[2];
#pragma unroll
        for (int m = 0; m < 2; ++m)
            af[m] = *reinterpret_cast<const s8v*>(
                w8b + (size_t)(((j * 4 + h) * 32 + m * 16 + q) * 8));
        int pos = w * 16 + q + 2 * j;
        s8v bf = *reinterpret_cast<const s8v*>(lds + pos * 64 + ((h ^ ((pos >> 1) & 3)) << 4));
        acc[0] = __builtin_amdgcn_mfma_f32_16x16x32_bf16(af[0], bf, acc[0], 0, 0, 0);
        acc[1] = __builtin_amdgcn_mfma_f32_16x16x32_bf16(af[1], bf, acc[1], 0, 0, 0);
    }

    // scatter D-frags to LDS rowbuf (pos = x+3, slot = g ^ ((pos>>1)&3))
    int xx = w * 16 + q;
    if (xx < 56) {
        int pos = xx + 3;
#pragma unroll
        for (int m = 0; m < 2; ++m) {
#pragma unroll
            for (int r = 0; r < 4; ++r) {
                int co = m * 16 + h * 4 + r;
                __hip_bfloat16 bv = __float2bfloat16(acc[m][r]);
                *(unsigned short*)(rowbuf + pos * 64 + (((co >> 3) ^ ((pos >> 1) & 3)) << 4) +
                                   (co & 7) * 2) = *(unsigned short*)&bv;
            }
        }
    }
    __syncthreads();
    // coalesced copy rowbuf -> t8T row (280 x 16B)
    char* rowo = t8T + (size_t)(n * 56 + y) * 4480;
    for (int u = t; u < 280; u += 256)
        *reinterpret_cast<s8v*>(rowo + u * 16) = *reinterpret_cast<const s8v*>(rowbuf + u * 16);
}

// ---------------- MFMA fused kernel: t8T -> t15 -> t16 + t14 -> out ----------------
// (round-7 m4 structure + s_setprio around MFMA cluster)
// grid 896 (n, y0=2*(b%28)), block 512 = 8 waves. rg = w>>2 row (y0+rg), co0 =
// (w&3)*64. Stage 6 t8T rows; contiguous kk K-loop with 1-deep A prefetch;
// shuffle epilogue (t16+t14), coalesced plain f32 stores.
__global__ __launch_bounds__(512) void k_t15m4(const char* __restrict__ t8T,
                                               const unsigned short* __restrict__ Wfb,
                                               const float* __restrict__ w16,
                                               const float* __restrict__ t14,
                                               float* __restrict__ out) {
    __shared__ __align__(16) char lds[26880];
    const int t = threadIdx.x;
    const int b = blockIdx.x;
    const int n = b / 28, y0 = (b % 28) * 2;
    const int l = t & 63, h = l >> 4, q = l & 15;
    const int w = t >> 6, rg = w >> 2;
    const int y = y0 + rg;
    const int co0 = (w & 3) * 64;

    // ---- stage 6 t8T rows y0-2 .. y0+3 (linear 16B copies) ----
    for (int e = t; e < 1680; e += 512) {
        int ridx = e / 280, u = e - ridx * 280;
        int yy = y0 - 2 + ridx;
        if (yy >= 0 && yy < 56)
            *reinterpret_cast<s8v*>(lds + ridx * 4480 + u * 16) =
                *reinterpret_cast<const s8v*>(t8T + (size_t)(n * 56 + yy) * 4480 + u * 16);
    }
    __syncthreads();

    f32x4 acc[4][4];
#pragma unroll
    for (int m = 0; m < 4; ++m)
#pragma unroll
        for (int nt = 0; nt < 4; ++nt)
            acc[m][nt] = (f32x4)0.f;

    // valid dy are contiguous: kk in [kklo, kkhi)
    const int kklo = (y >= 2) ? 0 : 7;
    const int kkhi = (y <= 53) ? 21 : 14;

    s8v af[4];
#pragma unroll
    for (int m = 0; m < 4; ++m)
        af[m] = *reinterpret_cast<const s8v*>(
            Wfb + (size_t)kklo * 8192 + (co0 + m * 16 + q) * 32 + h * 8);

    for (int kk = kklo; kk < kkhi; ++kk) {
        const int dy = kk / 7, dx = kk - dy * 7;
        const char* bbase = lds + (rg + 2 * dy) * 4480;
        s8v bf[4];
#pragma unroll
        for (int nt = 0; nt < 4; ++nt) {
            int xp = nt * 16 + q + dx;
            bf[nt] = *reinterpret_cast<const s8v*>(bbase + xp * 64 + ((h ^ ((xp >> 1) & 3)) << 4));
        }
        s8v afn[4];
        if (kk + 1 < kkhi) {
#pragma unroll
            for (int m = 0; m < 4; ++m)
                afn[m] = *reinterpret_cast<const s8v*>(
                    Wfb + (size_t)(kk + 1) * 8192 + (co0 + m * 16 + q) * 32 + h * 8);
        }
        __builtin_amdgcn_s_setprio(1);
#pragma unroll
        for (int nt = 0; nt < 4; ++nt)
#pragma unroll
            for (int m = 0; m < 4; ++m)
                acc[m][nt] = __builtin_amdgcn_mfma_f32_16x16x32_bf16(af[m], bf[nt], acc[m][nt], 0, 0, 0);
        __builtin_amdgcn_s_setprio(0);
#pragma unroll
        for (int m = 0; m < 4; ++m) af[m] = afn[m];
    }

    // ---- t16 + t14 epilogue: in-register x+-3 via shuffles, coalesced stores ----
    const float* t14r = t14 + (size_t)(n * 56 + y) * 56;
    float t14v[4];
#pragma unroll
    for (int nt = 0; nt < 4; ++nt) {
        int xx = nt * 16 + q;
        t14v[nt] = (xx < 56) ? t14r[xx] : 0.f;
    }
    const int srcm = (l & 48) | ((q + 13) & 15);
    const int srcp = (l & 48) | ((q + 3) & 15);
#pragma unroll
    for (int m = 0; m < 4; ++m) {
#pragma unroll
        for (int r = 0; r < 4; ++r) {
            int co = co0 + m * 16 + h * 4 + r;
            float wa = w16[co * 3], wb = w16[co * 3 + 1], wc = w16[co * 3 + 2];
            float v[4], rm[4], rp[4];
#pragma unroll
            for (int nt = 0; nt < 4; ++nt) v[nt] = acc[m][nt][r];
#pragma unroll
            for (int nt = 0; nt < 4; ++nt) {
                rm[nt] = __shfl(v[nt], srcm, 64);
                rp[nt] = __shfl(v[nt], srcp, 64);
            }
            float* orow = out + ((size_t)(n * 256 + co) * 56 + y) * 56;
#pragma unroll
            for (int nt = 0; nt < 4; ++nt) {
                int xx = nt * 16 + q;
                float vm = (q >= 3) ? rm[nt] : (nt > 0 ? rm[nt - 1] : 0.f);
                float vp = (q < 13) ? rp[nt] : (nt < 3 ? rp[nt + 1] : 0.f);
                float s = v[nt] * wb + t14v[nt];
                s += (xx >= 3) ? vm * wa : 0.f;
                s += (xx <= 52) ? vp * wc : 0.f;
                if (xx < 56) orow[xx] = s;
            }
        }
    }
}

extern "C" void kernel_launch(void* const* d_in, const int* in_sizes, int n_in,
                              void* d_out, int out_size, void* d_ws, size_t ws_size,
                              hipStream_t stream) {
    const float* x   = (const float*)d_in[0];
    const float* w1  = (const float*)d_in[1];
    const float* p2w = (const float*)d_in[2];
    const float* w3  = (const float*)d_in[3];
    const float* w4  = (const float*)d_in[4];
    const float* w5  = (const float*)d_in[5];
    const float* w8  = (const float*)d_in[6];
    const float* w12 = (const float*)d_in[7];
    const float* w14 = (const float*)d_in[8];
    const float* w15 = (const float*)d_in[9];
    const float* w16 = (const float*)d_in[10];
    float* out = (float*)d_out;

    float* ws = (float*)d_ws;
    float* t1   = ws;                  // 3211264 f32
    char*  t8T  = (char*)(t1 + 3211264);  // 8,028,160 B
    float* t4   = t1 + 2 * 3211264;    // 100352
    float* t14v = t4 + 100352;         // 100352
    float* W34  = t14v + 100352;       // 288
    __hip_bfloat16* Wfb = (__hip_bfloat16*)(W34 + 288);   // 172032 bf16
    __hip_bfloat16* w1b = Wfb + 172032;                   // 24576 bf16
    __hip_bfloat16* w8b = w1b + 24576;                    // 7168 bf16

    fuse_small<<<128, 256, 0, stream>>>(w3, w4, w1, w8, W34, w1b, w8b);
    fuse_w1215b<<<672, 256, 0, stream>>>(w15, w12, Wfb);

    k_t1f<<<1792, 256, 0, stream>>>(x, (const unsigned short*)w1b, t1);
    k_t4<<<448, 256, 0, stream>>>(t1, W34, t4);
    k_pt<<<448, 256, 0, stream>>>(t4, w14, t14v);
    k_t58<<<1792, 256, 0, stream>>>(t1, p2w, w5, (const unsigned short*)w8b, t8T);
    k_t15m4<<<896, 512, 0, stream>>>(t8T, (const unsigned short*)Wfb, w16, t14v, out);
}

// Round 11
// 214.524 us; speedup vs baseline: 1.0671x; 1.0123x over previous
//
#include <hip/hip_runtime.h>
#include <hip/hip_bf16.h>
#include <cstddef>

typedef __attribute__((ext_vector_type(8))) short s8v;
typedef __attribute__((ext_vector_type(4))) float f32x4;

// ---------------- L1: merged small repacks: W34 (288), w1b (24576), w8b (7168) ----------------
__global__ void fuse_small(const float* __restrict__ w3, const float* __restrict__ w4,
                           const float* __restrict__ w1, const float* __restrict__ w8,
                           float* __restrict__ W34, __hip_bfloat16* __restrict__ w1b,
                           __hip_bfloat16* __restrict__ w8b) {
    int idx = blockIdx.x * blockDim.x + threadIdx.x;
    if (idx < 288) {
        int ci = idx / 9, k1 = (idx / 3) % 3, k2 = idx % 3;
        float s = 0.f;
        for (int co = 0; co < 256; ++co)
            s += w3[(co * 32 + ci) * 3 + k1] * w4[co * 3 + k2];
        W34[idx] = s;
    }
    int i1 = idx - 512;
    if (i1 >= 0 && i1 < 24576) {
        int j = i1 & 7, co = (i1 >> 3) & 31, h = (i1 >> 8) & 3, c = (i1 >> 10) & 7, k = i1 >> 13;
        int ci = c * 32 + h * 8 + j;
        w1b[i1] = __float2bfloat16(w1[(co * 256 + ci) * 3 + k]);
    }
    int i2 = idx - 25600;
    if (i2 >= 0 && i2 < 7168) {
        int jj = i2 & 7, co = (i2 >> 3) & 31, h = (i2 >> 8) & 3, j = i2 >> 10;
        w8b[i2] = __float2bfloat16(w8[co * 224 + (h * 8 + jj) * 7 + j]);
    }
}

// ---------------- L2: t1 fused MFMA: conv 256->32, 3 w-taps dil 3 ----------------
// grid 1792 (n,y), block 256 = 4 waves. Wave w owns px quarter, full K, barrier-free.
__global__ __launch_bounds__(256) void k_t1f(const float* __restrict__ x,
                                             const unsigned short* __restrict__ w1b,
                                             float* __restrict__ t1) {
    __shared__ __align__(16) char lds[35840];
    const int t = threadIdx.x, b = blockIdx.x;
    const int n = b / 56, y = b % 56;
    const int w = t >> 6, l = t & 63, h = l >> 4, q = l & 15;
    const float* xr = x + (size_t)(n * 256) * 3136 + y * 56;

    // halo zeros: pos {0,1,2,59..69} x 32 g
#pragma unroll
    for (int it = 0; it < 2; ++it) {
        int u = it * 256 + t;
        if (u < 448) {
            int pi = u >> 5, g = u & 31;
            int pos = (pi < 3) ? pi : (56 + pi);
            *reinterpret_cast<s8v*>(lds + pos * 512 + ((g ^ (pos & 15)) << 4)) = (s8v)0;
        }
    }
    // coalesced stage: 1792 units (ci-pair, xq), packed b32 LDS writes
#pragma unroll 2
    for (int it = 0; it < 7; ++it) {
        int u = it * 256 + t;
        int c2 = u / 14, xq = u % 14;
        int ci = c2 * 2;
        float4 a = *(const float4*)(xr + (size_t)ci * 3136 + xq * 4);
        float4 bv = *(const float4*)(xr + (size_t)(ci + 1) * 3136 + xq * 4);
        int g = ci >> 3, lo = (ci & 7) * 2;
#pragma unroll
        for (int j = 0; j < 4; ++j) {
            int pos = xq * 4 + j + 3;
            __hip_bfloat16 b0 = __float2bfloat16(((const float*)&a)[j]);
            __hip_bfloat16 b1 = __float2bfloat16(((const float*)&bv)[j]);
            unsigned int wd = (unsigned int)(*(unsigned short*)&b0) |
                              ((unsigned int)(*(unsigned short*)&b1) << 16);
            *(unsigned int*)(lds + pos * 512 + ((g ^ (pos & 15)) << 4) + lo) = wd;
        }
    }
    __syncthreads();

    f32x4 acc[2];
    acc[0] = (f32x4)0.f;
    acc[1] = (f32x4)0.f;

    for (int c = 0; c < 8; ++c) {
        const int g = c * 4 + h;
#pragma unroll
        for (int k = 0; k < 3; ++k) {
            s8v af[2];
#pragma unroll
            for (int m = 0; m < 2; ++m)
                af[m] = *reinterpret_cast<const s8v*>(
                    w1b + (size_t)((((k * 8 + c) * 4 + h) * 32 + m * 16 + q) * 8));
            int pos = w * 16 + q + 3 * k;
            s8v bf = *reinterpret_cast<const s8v*>(lds + pos * 512 + ((g ^ (pos & 15)) << 4));
            acc[0] = __builtin_amdgcn_mfma_f32_16x16x32_bf16(af[0], bf, acc[0], 0, 0, 0);
            acc[1] = __builtin_amdgcn_mfma_f32_16x16x32_bf16(af[1], bf, acc[1], 0, 0, 0);
        }
    }

    int px = w * 16 + q;
    if (px < 56) {
#pragma unroll
        for (int m = 0; m < 2; ++m)
#pragma unroll
            for (int r = 0; r < 4; ++r)
                t1[((size_t)(n * 32 + m * 16 + h * 4 + r) * 56 + y) * 56 + px] = acc[m][r];
    }
}

// ---------------- L3: merged mid kernel ----------------
// blocks [0,1792): t5+t8 MFMA -> t8T;  [1792,2464): fuse_w1215b;  [2464,2912): t4.
__global__ __launch_bounds__(256) void k_mid(const float* __restrict__ t1,
                                             const float* __restrict__ p2w,
                                             const float* __restrict__ w5,
                                             const unsigned short* __restrict__ w8b,
                                             const float* __restrict__ w15,
                                             const float* __restrict__ w12,
                                             const float* __restrict__ W34,
                                             char* __restrict__ t8T,
                                             __hip_bfloat16* __restrict__ Wfb,
                                             float* __restrict__ t4) {
    __shared__ __align__(16) char lds[9344];
    const int t = threadIdx.x, b = blockIdx.x;

    if (b >= 2464) {  // ---- t4 role ----
        int by = b - 2464;
        int n = by / 14;
        int y = (by % 14) * 4 + (t >> 6);
        int px = t & 63;
        if (px >= 56) return;
        float acc = 0.f;
#pragma unroll 4
        for (int ci = 0; ci < 32; ++ci) {
#pragma unroll
            for (int k1 = 0; k1 < 3; ++k1) {
                int yy = y + 2 * k1 - 2;
                if (yy < 0 || yy >= 56) continue;
                const float* r = t1 + ((size_t)(n * 32 + ci) * 56 + yy) * 56;
#pragma unroll
                for (int k2 = 0; k2 < 3; ++k2) {
                    int xx = px + 3 * k2 - 3;
                    if (xx >= 0 && xx < 56)
                        acc += r[xx] * W34[ci * 9 + k1 * 3 + k2];
                }
            }
        }
        t4[(size_t)(n * 56 + y) * 56 + px] = acc;
        return;
    }
    if (b >= 1792) {  // ---- fuse_w1215b role ----
        int idx = (b - 1792) * 256 + t;
        int ci = idx & 31, co = (idx >> 5) & 255, kk = idx >> 13;
        int dy = kk / 7, dx = kk % 7;
        float s = 0.f;
#pragma unroll 8
        for (int m = 0; m < 256; ++m)
            s += w15[co * 768 + m * 3 + dy] * w12[(m * 32 + ci) * 7 + dx];
        Wfb[idx] = __float2bfloat16(s);
        return;
    }

    // ---- t5+t8 MFMA role ----
    const int n = b / 56, y = b % 56;
    const int w = t >> 6, l = t & 63, h = l >> 4, q = l & 15;
    const float* t1b = t1 + (size_t)(n * 32) * 3136;
    char* rowbuf = lds + 4864;

    if (t < 80) {
        int ph = t >> 2, g = t & 3;
        int pos = (ph < 6) ? ph : (56 + ph);
        *reinterpret_cast<s8v*>(lds + pos * 64 + ((g ^ ((pos >> 1) & 3)) << 4)) = (s8v)0;
    }
    if (t >= 80 && t < 136) {
        int u = t - 80;
        int ph = u >> 2, g = u & 3;
        int pos = (ph < 3) ? ph : (56 + ph);
        *reinterpret_cast<s8v*>(rowbuf + pos * 64 + ((g ^ ((pos >> 1) & 3)) << 4)) = (s8v)0;
    }
#pragma unroll
    for (int it = 0; it < 2; ++it) {
        int u = it * 256 + t;
        if (u < 448) {
            int ci = u / 14, xq = u % 14;
            float sc = p2w[ci];
            float4 s = {0.f, 0.f, 0.f, 0.f};
#pragma unroll
            for (int k = 0; k < 3; ++k) {
                int yy = y + 3 * k - 3;
                if (yy < 0 || yy >= 56) continue;
                float wv = w5[ci * 3 + k] * sc;
                float4 v = *(const float4*)(t1b + (size_t)ci * 3136 + yy * 56 + xq * 4);
                s.x += wv * v.x; s.y += wv * v.y; s.z += wv * v.z; s.w += wv * v.w;
            }
            int g = ci >> 3, lo = (ci & 7) * 2;
#pragma unroll
            for (int j = 0; j < 4; ++j) {
                int pos = xq * 4 + j + 6;
                __hip_bfloat16 bv = __float2bfloat16(((const float*)&s)[j]);
                *(unsigned short*)(lds + pos * 64 + ((g ^ ((pos >> 1) & 3)) << 4) + lo) =
                    *(unsigned short*)&bv;
            }
        }
    }
    __syncthreads();

    f32x4 acc[2];
    acc[0] = (f32x4)0.f; acc[1] = (f32x4)0.f;
#pragma unroll
    for (int j = 0; j < 7; ++j) {
        s8v af[2];
#pragma unroll
        for (int m = 0; m < 2; ++m)
            af[m] = *reinterpret_cast<const s8v*>(
                w8b + (size_t)(((j * 4 + h) * 32 + m * 16 + q) * 8));
        int pos = w * 16 + q + 2 * j;
        s8v bf = *reinterpret_cast<const s8v*>(lds + pos * 64 + ((h ^ ((pos >> 1) & 3)) << 4));
        acc[0] = __builtin_amdgcn_mfma_f32_16x16x32_bf16(af[0], bf, acc[0], 0, 0, 0);
        acc[1] = __builtin_amdgcn_mfma_f32_16x16x32_bf16(af[1], bf, acc[1], 0, 0, 0);
    }

    int xx = w * 16 + q;
    if (xx < 56) {
        int pos = xx + 3;
#pragma unroll
        for (int m = 0; m < 2; ++m) {
#pragma unroll
            for (int r = 0; r < 4; ++r) {
                int co = m * 16 + h * 4 + r;
                __hip_bfloat16 bv = __float2bfloat16(acc[m][r]);
                *(unsigned short*)(rowbuf + pos * 64 + (((co >> 3) ^ ((pos >> 1) & 3)) << 4) +
                                   (co & 7) * 2) = *(unsigned short*)&bv;
            }
        }
    }
    __syncthreads();
    char* rowo = t8T + (size_t)(n * 56 + y) * 4480;
    for (int u = t; u < 280; u += 256)
        *reinterpret_cast<s8v*>(rowo + u * 16) = *reinterpret_cast<const s8v*>(rowbuf + u * 16);
}

// ---------------- L4: t8T -> t15 -> t16 + (pool->t11->t14 from t4) -> out ----------------
// grid 896 (n, y0=2*(b%28)), block 512 = 8 waves. Prologue computes t14 rows
// y0,y0+1 from t4 via LDS R/T slabs (k_pt math inlined); w16 preloaded to LDS.
// K-loop = m4 structure (1-deep A prefetch); shuffle epilogue; plain stores.
__global__ __launch_bounds__(512) void k_t15p(const char* __restrict__ t8T,
                                              const unsigned short* __restrict__ Wfb,
                                              const float* __restrict__ w16,
                                              const float* __restrict__ w14,
                                              const float* __restrict__ t4,
                                              float* __restrict__ out) {
    __shared__ __align__(16) char lds[33024];
    float* Rr   = (float*)(lds + 26880);  // [6][64]
    float* Tt   = (float*)(lds + 28416);  // [4][64]
    float* t14l = (float*)(lds + 29440);  // [2][64]
    float* w16l = (float*)(lds + 29952);  // [768]
    const int t = threadIdx.x;
    const int b = blockIdx.x;
    const int n = b / 28, y0 = (b % 28) * 2;
    const int l = t & 63, h = l >> 4, q = l & 15;
    const int w = t >> 6, rg = w >> 2;
    const int y = y0 + rg;
    const int co0 = (w & 3) * 64;
    const float* t4b = t4 + (size_t)n * 3136;

    // ---- stage 6 t8T rows ----
    for (int e = t; e < 1680; e += 512) {
        int ridx = e / 280, u = e - ridx * 280;
        int yy = y0 - 2 + ridx;
        if (yy >= 0 && yy < 56)
            *reinterpret_cast<s8v*>(lds + ridx * 4480 + u * 16) =
                *reinterpret_cast<const s8v*>(t8T + (size_t)(n * 56 + yy) * 4480 + u * 16);
    }
    // ---- w16 preload ----
    for (int e = t; e < 768; e += 512) w16l[e] = w16[e];
    // ---- pool pass 1: R rows yc = y0-2 .. y0+3 ----
    for (int e = t; e < 336; e += 512) {
        int ridx = e / 56, xx = e % 56;
        int yc = y0 - 2 + ridx;
        float rv = 0.f;
        if (yc >= 0 && yc < 56) {
            float mm = -3.4e38f;
#pragma unroll
            for (int i = 0; i < 7; ++i) {
                int yy = yc + 3 * i - 9;
                float v = (yy >= 0 && yy < 56) ? t4b[(size_t)yy * 56 + xx] : 0.f;
                mm = fmaxf(mm, v);
            }
            rv = fmaxf(mm, 0.f);
        }
        Rr[ridx * 64 + xx] = rv;
    }
    __syncthreads();
    // ---- pool pass 2: T (t11) rows yt = y0-1 .. y0+2 ----
    for (int e = t; e < 224; e += 512) {
        int ti = e / 56, px = e % 56;
        int yt = y0 - 1 + ti;
        float s = 0.f;
        if (yt >= 0 && yt < 56) {
#pragma unroll
            for (int dy = 0; dy < 3; ++dy) {
                int yr = yt + dy - 1;
                if (yr < 0 || yr >= 56) continue;
                int row = yr - (y0 - 2);
#pragma unroll
                for (int j = 0; j < 7; ++j) {
                    int xx = px + 3 * j - 9;
                    if (xx >= 0 && xx < 56) s += Rr[row * 64 + xx];
                }
            }
            s *= (1.f / 21.f);
        }
        Tt[ti * 64 + px] = s;
    }
    __syncthreads();
    // ---- pool pass 3: t14 rows y0, y0+1 ----
    for (int e = t; e < 112; e += 512) {
        int yi = e / 56, px = e % 56;
        int yy0 = y0 + yi;
        float s = 0.f;
#pragma unroll
        for (int dy = 0; dy < 3; ++dy) {
            int yy = yy0 + dy - 1;
            if (yy < 0 || yy >= 56) continue;
            int row = yy - (y0 - 1);
#pragma unroll
            for (int dx = 0; dx < 3; ++dx) {
                int xx = px + dx - 1;
                if (xx < 0 || xx >= 56) continue;
                s += Tt[row * 64 + xx] * w14[dy * 3 + dx];
            }
        }
        t14l[yi * 64 + px] = s;
    }
    __syncthreads();

    f32x4 acc[4][4];
#pragma unroll
    for (int m = 0; m < 4; ++m)
#pragma unroll
        for (int nt = 0; nt < 4; ++nt)
            acc[m][nt] = (f32x4)0.f;

    const int kklo = (y >= 2) ? 0 : 7;
    const int kkhi = (y <= 53) ? 21 : 14;

    s8v af[4];
#pragma unroll
    for (int m = 0; m < 4; ++m)
        af[m] = *reinterpret_cast<const s8v*>(
            Wfb + (size_t)kklo * 8192 + (co0 + m * 16 + q) * 32 + h * 8);

    for (int kk = kklo; kk < kkhi; ++kk) {
        const int dy = kk / 7, dx = kk - dy * 7;
        const char* bbase = lds + (rg + 2 * dy) * 4480;
        s8v bf[4];
#pragma unroll
        for (int nt = 0; nt < 4; ++nt) {
            int xp = nt * 16 + q + dx;
            bf[nt] = *reinterpret_cast<const s8v*>(bbase + xp * 64 + ((h ^ ((xp >> 1) & 3)) << 4));
        }
        s8v afn[4];
        if (kk + 1 < kkhi) {
#pragma unroll
            for (int m = 0; m < 4; ++m)
                afn[m] = *reinterpret_cast<const s8v*>(
                    Wfb + (size_t)(kk + 1) * 8192 + (co0 + m * 16 + q) * 32 + h * 8);
        }
#pragma unroll
        for (int nt = 0; nt < 4; ++nt)
#pragma unroll
            for (int m = 0; m < 4; ++m)
                acc[m][nt] = __builtin_amdgcn_mfma_f32_16x16x32_bf16(af[m], bf[nt], acc[m][nt], 0, 0, 0);
#pragma unroll
        for (int m = 0; m < 4; ++m) af[m] = afn[m];
    }

    // ---- t16 + t14 epilogue ----
    float t14v[4];
#pragma unroll
    for (int nt = 0; nt < 4; ++nt) {
        int xx = nt * 16 + q;
        t14v[nt] = (xx < 56) ? t14l[rg * 64 + xx] : 0.f;
    }
    const int srcm = (l & 48) | ((q + 13) & 15);
    const int srcp = (l & 48) | ((q + 3) & 15);
#pragma unroll
    for (int m = 0; m < 4; ++m) {
#pragma unroll
        for (int r = 0; r < 4; ++r) {
            int co = co0 + m * 16 + h * 4 + r;
            float wa = w16l[co * 3], wb = w16l[co * 3 + 1], wc = w16l[co * 3 + 2];
            float v[4], rm[4], rp[4];
#pragma unroll
            for (int nt = 0; nt < 4; ++nt) v[nt] = acc[m][nt][r];
#pragma unroll
            for (int nt = 0; nt < 4; ++nt) {
                rm[nt] = __shfl(v[nt], srcm, 64);
                rp[nt] = __shfl(v[nt], srcp, 64);
            }
            float* orow = out + ((size_t)(n * 256 + co) * 56 + y) * 56;
#pragma unroll
            for (int nt = 0; nt < 4; ++nt) {
                int xx = nt * 16 + q;
                float vm = (q >= 3) ? rm[nt] : (nt > 0 ? rm[nt - 1] : 0.f);
                float vp = (q < 13) ? rp[nt] : (nt < 3 ? rp[nt + 1] : 0.f);
                float s = v[nt] * wb + t14v[nt];
                s += (xx >= 3) ? vm * wa : 0.f;
                s += (xx <= 52) ? vp * wc : 0.f;
                if (xx < 56) orow[xx] = s;
            }
        }
    }
}

extern "C" void kernel_launch(void* const* d_in, const int* in_sizes, int n_in,
                              void* d_out, int out_size, void* d_ws, size_t ws_size,
                              hipStream_t stream) {
    const float* x   = (const float*)d_in[0];
    const float* w1  = (const float*)d_in[1];
    const float* p2w = (const float*)d_in[2];
    const float* w3  = (const float*)d_in[3];
    const float* w4  = (const float*)d_in[4];
    const float* w5  = (const float*)d_in[5];
    const float* w8  = (const float*)d_in[6];
    const float* w12 = (const float*)d_in[7];
    const float* w14 = (const float*)d_in[8];
    const float* w15 = (const float*)d_in[9];
    const float* w16 = (const float*)d_in[10];
    float* out = (float*)d_out;

    float* ws = (float*)d_ws;
    float* t1   = ws;                      // 3211264 f32
    char*  t8T  = (char*)(t1 + 3211264);   // 8,028,160 B
    float* t4   = t1 + 2 * 3211264;        // 100352 f32
    float* W34  = t4 + 100352;             // 288 f32
    __hip_bfloat16* Wfb = (__hip_bfloat16*)(W34 + 288);   // 172032 bf16
    __hip_bfloat16* w1b = Wfb + 172032;                   // 24576 bf16
    __hip_bfloat16* w8b = w1b + 24576;                    // 7168 bf16

    fuse_small<<<128, 256, 0, stream>>>(w3, w4, w1, w8, W34, w1b, w8b);
    k_t1f<<<1792, 256, 0, stream>>>(x, (const unsigned short*)w1b, t1);
    k_mid<<<2912, 256, 0, stream>>>(t1, p2w, w5, (const unsigned short*)w8b,
                                    w15, w12, W34, t8T, Wfb, t4);
    k_t15p<<<896, 512, 0, stream>>>(t8T, (const unsigned short*)Wfb, w16, w14, t4, out);
}

// Round 12
// 160.876 us; speedup vs baseline: 1.4229x; 1.3335x over previous
//
#include <hip/hip_runtime.h>
#include <hip/hip_bf16.h>
#include <cstddef>

typedef __attribute__((ext_vector_type(8))) short s8v;
typedef __attribute__((ext_vector_type(4))) float f32x4;

// ---------------- L1: merged small repacks: W34 (288), w1b (24576), w8b (7168) ----------------
__global__ void fuse_small(const float* __restrict__ w3, const float* __restrict__ w4,
                           const float* __restrict__ w1, const float* __restrict__ w8,
                           float* __restrict__ W34, __hip_bfloat16* __restrict__ w1b,
                           __hip_bfloat16* __restrict__ w8b) {
    int idx = blockIdx.x * blockDim.x + threadIdx.x;
    if (idx < 288) {
        int ci = idx / 9, k1 = (idx / 3) % 3, k2 = idx % 3;
        float s = 0.f;
        for (int co = 0; co < 256; ++co)
            s += w3[(co * 32 + ci) * 3 + k1] * w4[co * 3 + k2];
        W34[idx] = s;
    }
    int i1 = idx - 512;
    if (i1 >= 0 && i1 < 24576) {
        int j = i1 & 7, co = (i1 >> 3) & 31, h = (i1 >> 8) & 3, c = (i1 >> 10) & 7, k = i1 >> 13;
        int ci = c * 32 + h * 8 + j;
        w1b[i1] = __float2bfloat16(w1[(co * 256 + ci) * 3 + k]);
    }
    int i2 = idx - 25600;
    if (i2 >= 0 && i2 < 7168) {
        int jj = i2 & 7, co = (i2 >> 3) & 31, h = (i2 >> 8) & 3, j = i2 >> 10;
        w8b[i2] = __float2bfloat16(w8[co * 224 + (h * 8 + jj) * 7 + j]);
    }
}

// ---------------- L2: t1 fused MFMA: conv 256->32, 3 w-taps dil 3 ----------------
// grid 1792 (n,y), block 256 = 4 waves. Wave w owns px quarter, full K, barrier-free.
__global__ __launch_bounds__(256) void k_t1f(const float* __restrict__ x,
                                             const unsigned short* __restrict__ w1b,
                                             float* __restrict__ t1) {
    __shared__ __align__(16) char lds[35840];
    const int t = threadIdx.x, b = blockIdx.x;
    const int n = b / 56, y = b % 56;
    const int w = t >> 6, l = t & 63, h = l >> 4, q = l & 15;
    const float* xr = x + (size_t)(n * 256) * 3136 + y * 56;

    // halo zeros: pos {0,1,2,59..69} x 32 g
#pragma unroll
    for (int it = 0; it < 2; ++it) {
        int u = it * 256 + t;
        if (u < 448) {
            int pi = u >> 5, g = u & 31;
            int pos = (pi < 3) ? pi : (56 + pi);
            *reinterpret_cast<s8v*>(lds + pos * 512 + ((g ^ (pos & 15)) << 4)) = (s8v)0;
        }
    }
    // coalesced stage: 1792 units (ci-pair, xq), packed b32 LDS writes
#pragma unroll 2
    for (int it = 0; it < 7; ++it) {
        int u = it * 256 + t;
        int c2 = u / 14, xq = u % 14;
        int ci = c2 * 2;
        float4 a = *(const float4*)(xr + (size_t)ci * 3136 + xq * 4);
        float4 bv = *(const float4*)(xr + (size_t)(ci + 1) * 3136 + xq * 4);
        int g = ci >> 3, lo = (ci & 7) * 2;
#pragma unroll
        for (int j = 0; j < 4; ++j) {
            int pos = xq * 4 + j + 3;
            __hip_bfloat16 b0 = __float2bfloat16(((const float*)&a)[j]);
            __hip_bfloat16 b1 = __float2bfloat16(((const float*)&bv)[j]);
            unsigned int wd = (unsigned int)(*(unsigned short*)&b0) |
                              ((unsigned int)(*(unsigned short*)&b1) << 16);
            *(unsigned int*)(lds + pos * 512 + ((g ^ (pos & 15)) << 4) + lo) = wd;
        }
    }
    __syncthreads();

    f32x4 acc[2];
    acc[0] = (f32x4)0.f;
    acc[1] = (f32x4)0.f;

    for (int c = 0; c < 8; ++c) {
        const int g = c * 4 + h;
#pragma unroll
        for (int k = 0; k < 3; ++k) {
            s8v af[2];
#pragma unroll
            for (int m = 0; m < 2; ++m)
                af[m] = *reinterpret_cast<const s8v*>(
                    w1b + (size_t)((((k * 8 + c) * 4 + h) * 32 + m * 16 + q) * 8));
            int pos = w * 16 + q + 3 * k;
            s8v bf = *reinterpret_cast<const s8v*>(lds + pos * 512 + ((g ^ (pos & 15)) << 4));
            acc[0] = __builtin_amdgcn_mfma_f32_16x16x32_bf16(af[0], bf, acc[0], 0, 0, 0);
            acc[1] = __builtin_amdgcn_mfma_f32_16x16x32_bf16(af[1], bf, acc[1], 0, 0, 0);
        }
    }

    int px = w * 16 + q;
    if (px < 56) {
#pragma unroll
        for (int m = 0; m < 2; ++m)
#pragma unroll
            for (int r = 0; r < 4; ++r)
                t1[((size_t)(n * 32 + m * 16 + h * 4 + r) * 56 + y) * 56 + px] = acc[m][r];
    }
}

// ---------------- L3: merged mid kernel ----------------
// blocks [0,1792): t5+t8 MFMA -> t8T (XCD-swizzled);
// [1792,2240): t4 (XCD-swizzled);  [2240,2912): fuse_w1215b (LDS-staged w12).
__global__ __launch_bounds__(256) void k_mid(const float* __restrict__ t1,
                                             const float* __restrict__ p2w,
                                             const float* __restrict__ w5,
                                             const unsigned short* __restrict__ w8b,
                                             const float* __restrict__ w15,
                                             const float* __restrict__ w12,
                                             const float* __restrict__ W34,
                                             char* __restrict__ t8T,
                                             __hip_bfloat16* __restrict__ Wfb,
                                             float* __restrict__ t4) {
    __shared__ __align__(16) char lds[14336];
    const int t = threadIdx.x, b = blockIdx.x;

    if (b >= 2240) {  // ---- fuse_w1215b role: LDS-staged w12, conflict-free reads ----
        int bb = b - 2240;           // 0..671
        int kk = bb >> 5;            // 0..20
        int oct = bb & 31;
        int dy = kk / 7, dx = kk - dy * 7;
        int ci = t & 31, col = t >> 5;
        int co = oct * 8 + col;
        float* w12s = (float*)lds;   // [16 m][32 ci][7 dx] = 3584 f32
        float s = 0.f;
        for (int c = 0; c < 16; ++c) {
            const float4* src = (const float4*)(w12 + c * 3584);
            for (int u = t; u < 896; u += 256)
                ((float4*)w12s)[u] = src[u];
            __syncthreads();
            int mbase = c * 16;
#pragma unroll
            for (int m = 0; m < 16; ++m) {
                float a = w15[co * 768 + (mbase + m) * 3 + dy];
                s += a * w12s[(m * 32 + ci) * 7 + dx];
            }
            __syncthreads();
        }
        Wfb[(size_t)kk * 8192 + co * 32 + ci] = __float2bfloat16(s);
        return;
    }
    if (b >= 1792) {  // ---- t4 role (XCD-swizzled: 448 = 8 x 56) ----
        int by = b - 1792;
        int v4 = (by & 7) * 56 + (by >> 3);
        int n = v4 / 14;
        int y = (v4 % 14) * 4 + (t >> 6);
        int px = t & 63;
        if (px >= 56) return;
        float acc = 0.f;
#pragma unroll 4
        for (int ci = 0; ci < 32; ++ci) {
#pragma unroll
            for (int k1 = 0; k1 < 3; ++k1) {
                int yy = y + 2 * k1 - 2;
                if (yy < 0 || yy >= 56) continue;
                const float* r = t1 + ((size_t)(n * 32 + ci) * 56 + yy) * 56;
#pragma unroll
                for (int k2 = 0; k2 < 3; ++k2) {
                    int xx = px + 3 * k2 - 3;
                    if (xx >= 0 && xx < 56)
                        acc += r[xx] * W34[ci * 9 + k1 * 3 + k2];
                }
            }
        }
        t4[(size_t)(n * 56 + y) * 56 + px] = acc;
        return;
    }

    // ---- t5+t8 MFMA role (XCD-swizzled: 1792 = 8 x 224) ----
    const int v = (b & 7) * 224 + (b >> 3);
    const int n = v / 56, y = v % 56;
    const int w = t >> 6, l = t & 63, h = l >> 4, q = l & 15;
    const float* t1b = t1 + (size_t)(n * 32) * 3136;
    char* rowbuf = lds + 4864;

    if (t < 80) {
        int ph = t >> 2, g = t & 3;
        int pos = (ph < 6) ? ph : (56 + ph);
        *reinterpret_cast<s8v*>(lds + pos * 64 + ((g ^ ((pos >> 1) & 3)) << 4)) = (s8v)0;
    }
    if (t >= 80 && t < 136) {
        int u = t - 80;
        int ph = u >> 2, g = u & 3;
        int pos = (ph < 3) ? ph : (56 + ph);
        *reinterpret_cast<s8v*>(rowbuf + pos * 64 + ((g ^ ((pos >> 1) & 3)) << 4)) = (s8v)0;
    }
#pragma unroll
    for (int it = 0; it < 2; ++it) {
        int u = it * 256 + t;
        if (u < 448) {
            int ci = u / 14, xq = u % 14;
            float sc = p2w[ci];
            float4 s = {0.f, 0.f, 0.f, 0.f};
#pragma unroll
            for (int k = 0; k < 3; ++k) {
                int yy = y + 3 * k - 3;
                if (yy < 0 || yy >= 56) continue;
                float wv = w5[ci * 3 + k] * sc;
                float4 vv = *(const float4*)(t1b + (size_t)ci * 3136 + yy * 56 + xq * 4);
                s.x += wv * vv.x; s.y += wv * vv.y; s.z += wv * vv.z; s.w += wv * vv.w;
            }
            int g = ci >> 3, lo = (ci & 7) * 2;
#pragma unroll
            for (int j = 0; j < 4; ++j) {
                int pos = xq * 4 + j + 6;
                __hip_bfloat16 bv = __float2bfloat16(((const float*)&s)[j]);
                *(unsigned short*)(lds + pos * 64 + ((g ^ ((pos >> 1) & 3)) << 4) + lo) =
                    *(unsigned short*)&bv;
            }
        }
    }
    __syncthreads();

    f32x4 acc[2];
    acc[0] = (f32x4)0.f; acc[1] = (f32x4)0.f;
#pragma unroll
    for (int j = 0; j < 7; ++j) {
        s8v af[2];
#pragma unroll
        for (int m = 0; m < 2; ++m)
            af[m] = *reinterpret_cast<const s8v*>(
                w8b + (size_t)(((j * 4 + h) * 32 + m * 16 + q) * 8));
        int pos = w * 16 + q + 2 * j;
        s8v bf = *reinterpret_cast<const s8v*>(lds + pos * 64 + ((h ^ ((pos >> 1) & 3)) << 4));
        acc[0] = __builtin_amdgcn_mfma_f32_16x16x32_bf16(af[0], bf, acc[0], 0, 0, 0);
        acc[1] = __builtin_amdgcn_mfma_f32_16x16x32_bf16(af[1], bf, acc[1], 0, 0, 0);
    }

    int xx = w * 16 + q;
    if (xx < 56) {
        int pos = xx + 3;
#pragma unroll
        for (int m = 0; m < 2; ++m) {
#pragma unroll
            for (int r = 0; r < 4; ++r) {
                int co = m * 16 + h * 4 + r;
                __hip_bfloat16 bv = __float2bfloat16(acc[m][r]);
                *(unsigned short*)(rowbuf + pos * 64 + (((co >> 3) ^ ((pos >> 1) & 3)) << 4) +
                                   (co & 7) * 2) = *(unsigned short*)&bv;
            }
        }
    }
    __syncthreads();
    char* rowo = t8T + (size_t)(n * 56 + y) * 4480;
    for (int u = t; u < 280; u += 256)
        *reinterpret_cast<s8v*>(rowo + u * 16) = *reinterpret_cast<const s8v*>(rowbuf + u * 16);
}

// ---------------- L4: t8T -> t15 -> t16 + (pool->t11->t14 from t4) -> out ----------------
// grid 896 (XCD-swizzled: 8 x 112), block 512 = 8 waves. Prologue computes t14
// rows y0,y0+1 from t4 in LDS; w16 preloaded. K-loop = m4 structure.
__global__ __launch_bounds__(512) void k_t15p(const char* __restrict__ t8T,
                                              const unsigned short* __restrict__ Wfb,
                                              const float* __restrict__ w16,
                                              const float* __restrict__ w14,
                                              const float* __restrict__ t4,
                                              float* __restrict__ out) {
    __shared__ __align__(16) char lds[33024];
    float* Rr   = (float*)(lds + 26880);  // [6][64]
    float* Tt   = (float*)(lds + 28416);  // [4][64]
    float* t14l = (float*)(lds + 29440);  // [2][64]
    float* w16l = (float*)(lds + 29952);  // [768]
    const int t = threadIdx.x;
    const int b = blockIdx.x;
    const int vb = (b & 7) * 112 + (b >> 3);
    const int n = vb / 28, y0 = (vb % 28) * 2;
    const int l = t & 63, h = l >> 4, q = l & 15;
    const int w = t >> 6, rg = w >> 2;
    const int y = y0 + rg;
    const int co0 = (w & 3) * 64;
    const float* t4b = t4 + (size_t)n * 3136;

    // ---- stage 6 t8T rows ----
    for (int e = t; e < 1680; e += 512) {
        int ridx = e / 280, u = e - ridx * 280;
        int yy = y0 - 2 + ridx;
        if (yy >= 0 && yy < 56)
            *reinterpret_cast<s8v*>(lds + ridx * 4480 + u * 16) =
                *reinterpret_cast<const s8v*>(t8T + (size_t)(n * 56 + yy) * 4480 + u * 16);
    }
    // ---- w16 preload ----
    for (int e = t; e < 768; e += 512) w16l[e] = w16[e];
    // ---- pool pass 1: R rows yc = y0-2 .. y0+3 ----
    for (int e = t; e < 336; e += 512) {
        int ridx = e / 56, xx = e % 56;
        int yc = y0 - 2 + ridx;
        float rv = 0.f;
        if (yc >= 0 && yc < 56) {
            float mm = -3.4e38f;
#pragma unroll
            for (int i = 0; i < 7; ++i) {
                int yy = yc + 3 * i - 9;
                float v = (yy >= 0 && yy < 56) ? t4b[(size_t)yy * 56 + xx] : 0.f;
                mm = fmaxf(mm, v);
            }
            rv = fmaxf(mm, 0.f);
        }
        Rr[ridx * 64 + xx] = rv;
    }
    __syncthreads();
    // ---- pool pass 2: T (t11) rows yt = y0-1 .. y0+2 ----
    for (int e = t; e < 224; e += 512) {
        int ti = e / 56, px = e % 56;
        int yt = y0 - 1 + ti;
        float s = 0.f;
        if (yt >= 0 && yt < 56) {
#pragma unroll
            for (int dy = 0; dy < 3; ++dy) {
                int yr = yt + dy - 1;
                if (yr < 0 || yr >= 56) continue;
                int row = yr - (y0 - 2);
#pragma unroll
                for (int j = 0; j < 7; ++j) {
                    int xx = px + 3 * j - 9;
                    if (xx >= 0 && xx < 56) s += Rr[row * 64 + xx];
                }
            }
            s *= (1.f / 21.f);
        }
        Tt[ti * 64 + px] = s;
    }
    __syncthreads();
    // ---- pool pass 3: t14 rows y0, y0+1 ----
    for (int e = t; e < 112; e += 512) {
        int yi = e / 56, px = e % 56;
        int yy0 = y0 + yi;
        float s = 0.f;
#pragma unroll
        for (int dy = 0; dy < 3; ++dy) {
            int yy = yy0 + dy - 1;
            if (yy < 0 || yy >= 56) continue;
            int row = yy - (y0 - 1);
#pragma unroll
            for (int dx = 0; dx < 3; ++dx) {
                int xx = px + dx - 1;
                if (xx < 0 || xx >= 56) continue;
                s += Tt[row * 64 + xx] * w14[dy * 3 + dx];
            }
        }
        t14l[yi * 64 + px] = s;
    }
    __syncthreads();

    f32x4 acc[4][4];
#pragma unroll
    for (int m = 0; m < 4; ++m)
#pragma unroll
        for (int nt = 0; nt < 4; ++nt)
            acc[m][nt] = (f32x4)0.f;

    const int kklo = (y >= 2) ? 0 : 7;
    const int kkhi = (y <= 53) ? 21 : 14;

    s8v af[4];
#pragma unroll
    for (int m = 0; m < 4; ++m)
        af[m] = *reinterpret_cast<const s8v*>(
            Wfb + (size_t)kklo * 8192 + (co0 + m * 16 + q) * 32 + h * 8);

    for (int kk = kklo; kk < kkhi; ++kk) {
        const int dy = kk / 7, dx = kk - dy * 7;
        const char* bbase = lds + (rg + 2 * dy) * 4480;
        s8v bf[4];
#pragma unroll
        for (int nt = 0; nt < 4; ++nt) {
            int xp = nt * 16 + q + dx;
            bf[nt] = *reinterpret_cast<const s8v*>(bbase + xp * 64 + ((h ^ ((xp >> 1) & 3)) << 4));
        }
        s8v afn[4];
        if (kk + 1 < kkhi) {
#pragma unroll
            for (int m = 0; m < 4; ++m)
                afn[m] = *reinterpret_cast<const s8v*>(
                    Wfb + (size_t)(kk + 1) * 8192 + (co0 + m * 16 + q) * 32 + h * 8);
        }
#pragma unroll
        for (int nt = 0; nt < 4; ++nt)
#pragma unroll
            for (int m = 0; m < 4; ++m)
                acc[m][nt] = __builtin_amdgcn_mfma_f32_16x16x32_bf16(af[m], bf[nt], acc[m][nt], 0, 0, 0);
#pragma unroll
        for (int m = 0; m < 4; ++m) af[m] = afn[m];
    }

    // ---- t16 + t14 epilogue ----
    float t14v[4];
#pragma unroll
    for (int nt = 0; nt < 4; ++nt) {
        int xx = nt * 16 + q;
        t14v[nt] = (xx < 56) ? t14l[rg * 64 + xx] : 0.f;
    }
    const int srcm = (l & 48) | ((q + 13) & 15);
    const int srcp = (l & 48) | ((q + 3) & 15);
#pragma unroll
    for (int m = 0; m < 4; ++m) {
#pragma unroll
        for (int r = 0; r < 4; ++r) {
            int co = co0 + m * 16 + h * 4 + r;
            float wa = w16l[co * 3], wb = w16l[co * 3 + 1], wc = w16l[co * 3 + 2];
            float v[4], rm[4], rp[4];
#pragma unroll
            for (int nt = 0; nt < 4; ++nt) v[nt] = acc[m][nt][r];
#pragma unroll
            for (int nt = 0; nt < 4; ++nt) {
                rm[nt] = __shfl(v[nt], srcm, 64);
                rp[nt] = __shfl(v[nt], srcp, 64);
            }
            float* orow = out + ((size_t)(n * 256 + co) * 56 + y) * 56;
#pragma unroll
            for (int nt = 0; nt < 4; ++nt) {
                int xx = nt * 16 + q;
                float vm = (q >= 3) ? rm[nt] : (nt > 0 ? rm[nt - 1] : 0.f);
                float vp = (q < 13) ? rp[nt] : (nt < 3 ? rp[nt + 1] : 0.f);
                float s = v[nt] * wb + t14v[nt];
                s += (xx >= 3) ? vm * wa : 0.f;
                s += (xx <= 52) ? vp * wc : 0.f;
                if (xx < 56) orow[xx] = s;
            }
        }
    }
}

extern "C" void kernel_launch(void* const* d_in, const int* in_sizes, int n_in,
                              void* d_out, int out_size, void* d_ws, size_t ws_size,
                              hipStream_t stream) {
    const float* x   = (const float*)d_in[0];
    const float* w1  = (const float*)d_in[1];
    const float* p2w = (const float*)d_in[2];
    const float* w3  = (const float*)d_in[3];
    const float* w4  = (const float*)d_in[4];
    const float* w5  = (const float*)d_in[5];
    const float* w8  = (const float*)d_in[6];
    const float* w12 = (const float*)d_in[7];
    const float* w14 = (const float*)d_in[8];
    const float* w15 = (const float*)d_in[9];
    const float* w16 = (const float*)d_in[10];
    float* out = (float*)d_out;

    float* ws = (float*)d_ws;
    float* t1   = ws;                      // 3211264 f32
    char*  t8T  = (char*)(t1 + 3211264);   // 8,028,160 B
    float* t4   = t1 + 2 * 3211264;        // 100352 f32
    float* W34  = t4 + 100352;             // 288 f32
    __hip_bfloat16* Wfb = (__hip_bfloat16*)(W34 + 288);   // 172032 bf16
    __hip_bfloat16* w1b = Wfb + 172032;                   // 24576 bf16
    __hip_bfloat16* w8b = w1b + 24576;                    // 7168 bf16

    fuse_small<<<128, 256, 0, stream>>>(w3, w4, w1, w8, W34, w1b, w8b);
    k_t1f<<<1792, 256, 0, stream>>>(x, (const unsigned short*)w1b, t1);
    k_mid<<<2912, 256, 0, stream>>>(t1, p2w, w5, (const unsigned short*)w8b,
                                    w15, w12, W34, t8T, Wfb, t4);
    k_t15p<<<896, 512, 0, stream>>>(t8T, (const unsigned short*)Wfb, w16, w14, t4, out);
}

// Round 13
// 160.324 us; speedup vs baseline: 1.4278x; 1.0034x over previous
//
#include <hip/hip_runtime.h>
#include <hip/hip_bf16.h>
#include <cstddef>

typedef __attribute__((ext_vector_type(8))) short s8v;
typedef __attribute__((ext_vector_type(4))) float f32x4;

// ---------------- L1: merged small repacks: W34 (288), w1b (24576), w8b (7168) ----------------
__global__ void fuse_small(const float* __restrict__ w3, const float* __restrict__ w4,
                           const float* __restrict__ w1, const float* __restrict__ w8,
                           float* __restrict__ W34, __hip_bfloat16* __restrict__ w1b,
                           __hip_bfloat16* __restrict__ w8b) {
    int idx = blockIdx.x * blockDim.x + threadIdx.x;
    if (idx < 288) {
        int ci = idx / 9, k1 = (idx / 3) % 3, k2 = idx % 3;
        float s = 0.f;
        for (int co = 0; co < 256; ++co)
            s += w3[(co * 32 + ci) * 3 + k1] * w4[co * 3 + k2];
        W34[idx] = s;
    }
    int i1 = idx - 512;
    if (i1 >= 0 && i1 < 24576) {
        int j = i1 & 7, co = (i1 >> 3) & 31, h = (i1 >> 8) & 3, c = (i1 >> 10) & 7, k = i1 >> 13;
        int ci = c * 32 + h * 8 + j;
        w1b[i1] = __float2bfloat16(w1[(co * 256 + ci) * 3 + k]);
    }
    int i2 = idx - 25600;
    if (i2 >= 0 && i2 < 7168) {
        int jj = i2 & 7, co = (i2 >> 3) & 31, h = (i2 >> 8) & 3, j = i2 >> 10;
        w8b[i2] = __float2bfloat16(w8[co * 224 + (h * 8 + jj) * 7 + j]);
    }
}

// ---------------- L2: t1 fused MFMA: conv 256->32, 3 w-taps dil 3 ----------------
__global__ __launch_bounds__(256) void k_t1f(const float* __restrict__ x,
                                             const unsigned short* __restrict__ w1b,
                                             float* __restrict__ t1) {
    __shared__ __align__(16) char lds[35840];
    const int t = threadIdx.x, b = blockIdx.x;
    const int n = b / 56, y = b % 56;
    const int w = t >> 6, l = t & 63, h = l >> 4, q = l & 15;
    const float* xr = x + (size_t)(n * 256) * 3136 + y * 56;

#pragma unroll
    for (int it = 0; it < 2; ++it) {
        int u = it * 256 + t;
        if (u < 448) {
            int pi = u >> 5, g = u & 31;
            int pos = (pi < 3) ? pi : (56 + pi);
            *reinterpret_cast<s8v*>(lds + pos * 512 + ((g ^ (pos & 15)) << 4)) = (s8v)0;
        }
    }
#pragma unroll 2
    for (int it = 0; it < 7; ++it) {
        int u = it * 256 + t;
        int c2 = u / 14, xq = u % 14;
        int ci = c2 * 2;
        float4 a = *(const float4*)(xr + (size_t)ci * 3136 + xq * 4);
        float4 bv = *(const float4*)(xr + (size_t)(ci + 1) * 3136 + xq * 4);
        int g = ci >> 3, lo = (ci & 7) * 2;
#pragma unroll
        for (int j = 0; j < 4; ++j) {
            int pos = xq * 4 + j + 3;
            __hip_bfloat16 b0 = __float2bfloat16(((const float*)&a)[j]);
            __hip_bfloat16 b1 = __float2bfloat16(((const float*)&bv)[j]);
            unsigned int wd = (unsigned int)(*(unsigned short*)&b0) |
                              ((unsigned int)(*(unsigned short*)&b1) << 16);
            *(unsigned int*)(lds + pos * 512 + ((g ^ (pos & 15)) << 4) + lo) = wd;
        }
    }
    __syncthreads();

    f32x4 acc[2];
    acc[0] = (f32x4)0.f;
    acc[1] = (f32x4)0.f;

    for (int c = 0; c < 8; ++c) {
        const int g = c * 4 + h;
#pragma unroll
        for (int k = 0; k < 3; ++k) {
            s8v af[2];
#pragma unroll
            for (int m = 0; m < 2; ++m)
                af[m] = *reinterpret_cast<const s8v*>(
                    w1b + (size_t)((((k * 8 + c) * 4 + h) * 32 + m * 16 + q) * 8));
            int pos = w * 16 + q + 3 * k;
            s8v bf = *reinterpret_cast<const s8v*>(lds + pos * 512 + ((g ^ (pos & 15)) << 4));
            acc[0] = __builtin_amdgcn_mfma_f32_16x16x32_bf16(af[0], bf, acc[0], 0, 0, 0);
            acc[1] = __builtin_amdgcn_mfma_f32_16x16x32_bf16(af[1], bf, acc[1], 0, 0, 0);
        }
    }

    int px = w * 16 + q;
    if (px < 56) {
#pragma unroll
        for (int m = 0; m < 2; ++m)
#pragma unroll
            for (int r = 0; r < 4; ++r)
                t1[((size_t)(n * 32 + m * 16 + h * 4 + r) * 56 + y) * 56 + px] = acc[m][r];
    }
}

// ---------------- L3: merged mid kernel ----------------
// blocks [0,1792): t5+t8 MFMA -> t8T (XCD-swizzled);
// [1792,2240): t4 (XCD-swizzled);  [2240,2912): fuse_w1215b (LDS-staged w12).
__global__ __launch_bounds__(256) void k_mid(const float* __restrict__ t1,
                                             const float* __restrict__ p2w,
                                             const float* __restrict__ w5,
                                             const unsigned short* __restrict__ w8b,
                                             const float* __restrict__ w15,
                                             const float* __restrict__ w12,
                                             const float* __restrict__ W34,
                                             char* __restrict__ t8T,
                                             __hip_bfloat16* __restrict__ Wfb,
                                             float* __restrict__ t4) {
    __shared__ __align__(16) char lds[14336];
    const int t = threadIdx.x, b = blockIdx.x;

    if (b >= 2240) {  // ---- fuse_w1215b role: LDS-staged w12, conflict-free reads ----
        int bb = b - 2240;           // 0..671
        int kk = bb >> 5;            // 0..20
        int oct = bb & 31;
        int dy = kk / 7, dx = kk - dy * 7;
        int ci = t & 31, col = t >> 5;
        int co = oct * 8 + col;
        float* w12s = (float*)lds;   // [16 m][32 ci][7 dx] = 3584 f32
        float s = 0.f;
        for (int c = 0; c < 16; ++c) {
            const float4* src = (const float4*)(w12 + c * 3584);
            for (int u = t; u < 896; u += 256)
                ((float4*)w12s)[u] = src[u];
            __syncthreads();
            int mbase = c * 16;
#pragma unroll
            for (int m = 0; m < 16; ++m) {
                float a = w15[co * 768 + (mbase + m) * 3 + dy];
                s += a * w12s[(m * 32 + ci) * 7 + dx];
            }
            __syncthreads();
        }
        Wfb[(size_t)kk * 8192 + co * 32 + ci] = __float2bfloat16(s);
        return;
    }
    if (b >= 1792) {  // ---- t4 role (XCD-swizzled: 448 = 8 x 56) ----
        int by = b - 1792;
        int v4 = (by & 7) * 56 + (by >> 3);
        int n = v4 / 14;
        int y = (v4 % 14) * 4 + (t >> 6);
        int px = t & 63;
        if (px >= 56) return;
        float acc = 0.f;
#pragma unroll 4
        for (int ci = 0; ci < 32; ++ci) {
#pragma unroll
            for (int k1 = 0; k1 < 3; ++k1) {
                int yy = y + 2 * k1 - 2;
                if (yy < 0 || yy >= 56) continue;
                const float* r = t1 + ((size_t)(n * 32 + ci) * 56 + yy) * 56;
#pragma unroll
                for (int k2 = 0; k2 < 3; ++k2) {
                    int xx = px + 3 * k2 - 3;
                    if (xx >= 0 && xx < 56)
                        acc += r[xx] * W34[ci * 9 + k1 * 3 + k2];
                }
            }
        }
        t4[(size_t)(n * 56 + y) * 56 + px] = acc;
        return;
    }

    // ---- t5+t8 MFMA role (XCD-swizzled: 1792 = 8 x 224) ----
    const int v = (b & 7) * 224 + (b >> 3);
    const int n = v / 56, y = v % 56;
    const int w = t >> 6, l = t & 63, h = l >> 4, q = l & 15;
    const float* t1b = t1 + (size_t)(n * 32) * 3136;
    char* rowbuf = lds + 4864;

    if (t < 80) {
        int ph = t >> 2, g = t & 3;
        int pos = (ph < 6) ? ph : (56 + ph);
        *reinterpret_cast<s8v*>(lds + pos * 64 + ((g ^ ((pos >> 1) & 3)) << 4)) = (s8v)0;
    }
    if (t >= 80 && t < 136) {
        int u = t - 80;
        int ph = u >> 2, g = u & 3;
        int pos = (ph < 3) ? ph : (56 + ph);
        *reinterpret_cast<s8v*>(rowbuf + pos * 64 + ((g ^ ((pos >> 1) & 3)) << 4)) = (s8v)0;
    }
#pragma unroll
    for (int it = 0; it < 2; ++it) {
        int u = it * 256 + t;
        if (u < 448) {
            int ci = u / 14, xq = u % 14;
            float sc = p2w[ci];
            float4 s = {0.f, 0.f, 0.f, 0.f};
#pragma unroll
            for (int k = 0; k < 3; ++k) {
                int yy = y + 3 * k - 3;
                if (yy < 0 || yy >= 56) continue;
                float wv = w5[ci * 3 + k] * sc;
                float4 vv = *(const float4*)(t1b + (size_t)ci * 3136 + yy * 56 + xq * 4);
                s.x += wv * vv.x; s.y += wv * vv.y; s.z += wv * vv.z; s.w += wv * vv.w;
            }
            int g = ci >> 3, lo = (ci & 7) * 2;
#pragma unroll
            for (int j = 0; j < 4; ++j) {
                int pos = xq * 4 + j + 6;
                __hip_bfloat16 bv = __float2bfloat16(((const float*)&s)[j]);
                *(unsigned short*)(lds + pos * 64 + ((g ^ ((pos >> 1) & 3)) << 4) + lo) =
                    *(unsigned short*)&bv;
            }
        }
    }
    __syncthreads();

    f32x4 acc[2];
    acc[0] = (f32x4)0.f; acc[1] = (f32x4)0.f;
#pragma unroll
    for (int j = 0; j < 7; ++j) {
        s8v af[2];
#pragma unroll
        for (int m = 0; m < 2; ++m)
            af[m] = *reinterpret_cast<const s8v*>(
                w8b + (size_t)(((j * 4 + h) * 32 + m * 16 + q) * 8));
        int pos = w * 16 + q + 2 * j;
        s8v bf = *reinterpret_cast<const s8v*>(lds + pos * 64 + ((h ^ ((pos >> 1) & 3)) << 4));
        acc[0] = __builtin_amdgcn_mfma_f32_16x16x32_bf16(af[0], bf, acc[0], 0, 0, 0);
        acc[1] = __builtin_amdgcn_mfma_f32_16x16x32_bf16(af[1], bf, acc[1], 0, 0, 0);
    }

    int xx = w * 16 + q;
    if (xx < 56) {
        int pos = xx + 3;
#pragma unroll
        for (int m = 0; m < 2; ++m) {
#pragma unroll
            for (int r = 0; r < 4; ++r) {
                int co = m * 16 + h * 4 + r;
                __hip_bfloat16 bv = __float2bfloat16(acc[m][r]);
                *(unsigned short*)(rowbuf + pos * 64 + (((co >> 3) ^ ((pos >> 1) & 3)) << 4) +
                                   (co & 7) * 2) = *(unsigned short*)&bv;
            }
        }
    }
    __syncthreads();
    char* rowo = t8T + (size_t)(n * 56 + y) * 4480;
    for (int u = t; u < 280; u += 256)
        *reinterpret_cast<s8v*>(rowo + u * 16) = *reinterpret_cast<const s8v*>(rowbuf + u * 16);
}

// ---------------- L4: t8T -> t15 -> t16 + (pool->t11->t14 from t4) -> out ----------------
// grid 1792 (XCD-swizzled: 8 x 224), block 512 = 8 waves. ONE row per block;
// wave w owns co slice [w*32, w*32+32) -> acc only 8 frags (32 AGPR) so
// ~25 waves/CU fit (vs 16 before). Stage 3 t8T rows (ridx = dy); pool/t14
// prologue for row y in LDS; K-loop with 1-deep A prefetch; shuffle epilogue.
__global__ __launch_bounds__(512) void k_t15q(const char* __restrict__ t8T,
                                              const unsigned short* __restrict__ Wfb,
                                              const float* __restrict__ w16,
                                              const float* __restrict__ w14,
                                              const float* __restrict__ t4,
                                              float* __restrict__ out) {
    __shared__ __align__(16) char lds[18816];
    float* Rr   = (float*)(lds + 13440);  // [5][64]
    float* Tt   = (float*)(lds + 14720);  // [3][64]
    float* t14l = (float*)(lds + 15488);  // [64]
    float* w16l = (float*)(lds + 15744);  // [768]
    const int t = threadIdx.x;
    const int b = blockIdx.x;
    const int vb = (b & 7) * 224 + (b >> 3);
    const int n = vb / 56, y = vb % 56;
    const int l = t & 63, h = l >> 4, q = l & 15;
    const int w = t >> 6;
    const int co0 = w * 32;
    const float* t4b = t4 + (size_t)n * 3136;

    // ---- stage 3 t8T rows y-2, y, y+2 (ridx = dy) ----
    for (int e = t; e < 840; e += 512) {
        int ridx = e / 280, u = e - ridx * 280;
        int yy = y + 2 * ridx - 2;
        if (yy >= 0 && yy < 56)
            *reinterpret_cast<s8v*>(lds + ridx * 4480 + u * 16) =
                *reinterpret_cast<const s8v*>(t8T + (size_t)(n * 56 + yy) * 4480 + u * 16);
    }
    // ---- w16 preload ----
    for (int e = t; e < 768; e += 512) w16l[e] = w16[e];
    // ---- pool pass 1: R rows yc = y-2 .. y+2 ----
    for (int e = t; e < 280; e += 512) {
        int ridx = e / 56, xx = e % 56;
        int yc = y - 2 + ridx;
        float rv = 0.f;
        if (yc >= 0 && yc < 56) {
            float mm = -3.4e38f;
#pragma unroll
            for (int i = 0; i < 7; ++i) {
                int yy = yc + 3 * i - 9;
                float v = (yy >= 0 && yy < 56) ? t4b[(size_t)yy * 56 + xx] : 0.f;
                mm = fmaxf(mm, v);
            }
            rv = fmaxf(mm, 0.f);
        }
        Rr[ridx * 64 + xx] = rv;
    }
    __syncthreads();
    // ---- pool pass 2: T (t11) rows yt = y-1 .. y+1 ----
    for (int e = t; e < 168; e += 512) {
        int ti = e / 56, px = e % 56;
        int yt = y - 1 + ti;
        float s = 0.f;
        if (yt >= 0 && yt < 56) {
#pragma unroll
            for (int dy = 0; dy < 3; ++dy) {
                int yr = yt + dy - 1;
                if (yr < 0 || yr >= 56) continue;
                int row = ti + dy;  // = yr - (y-2)
#pragma unroll
                for (int j = 0; j < 7; ++j) {
                    int xx = px + 3 * j - 9;
                    if (xx >= 0 && xx < 56) s += Rr[row * 64 + xx];
                }
            }
            s *= (1.f / 21.f);
        }
        Tt[ti * 64 + px] = s;
    }
    __syncthreads();
    // ---- pool pass 3: t14 row y ----
    if (t < 56) {
        int px = t;
        float s = 0.f;
#pragma unroll
        for (int dy = 0; dy < 3; ++dy) {
            int yy = y + dy - 1;
            if (yy < 0 || yy >= 56) continue;
#pragma unroll
            for (int dx = 0; dx < 3; ++dx) {
                int xx = px + dx - 1;
                if (xx < 0 || xx >= 56) continue;
                s += Tt[dy * 64 + xx] * w14[dy * 3 + dx];
            }
        }
        t14l[px] = s;
    }
    __syncthreads();

    f32x4 acc[2][4];
#pragma unroll
    for (int m = 0; m < 2; ++m)
#pragma unroll
        for (int nt = 0; nt < 4; ++nt)
            acc[m][nt] = (f32x4)0.f;

    const int kklo = (y >= 2) ? 0 : 7;
    const int kkhi = (y <= 53) ? 21 : 14;

    s8v af[2];
#pragma unroll
    for (int m = 0; m < 2; ++m)
        af[m] = *reinterpret_cast<const s8v*>(
            Wfb + (size_t)kklo * 8192 + (co0 + m * 16 + q) * 32 + h * 8);

    for (int kk = kklo; kk < kkhi; ++kk) {
        const int dy = kk / 7, dx = kk - dy * 7;
        const char* bbase = lds + dy * 4480;
        s8v bf[4];
#pragma unroll
        for (int nt = 0; nt < 4; ++nt) {
            int xp = nt * 16 + q + dx;
            bf[nt] = *reinterpret_cast<const s8v*>(bbase + xp * 64 + ((h ^ ((xp >> 1) & 3)) << 4));
        }
        s8v afn[2];
        if (kk + 1 < kkhi) {
#pragma unroll
            for (int m = 0; m < 2; ++m)
                afn[m] = *reinterpret_cast<const s8v*>(
                    Wfb + (size_t)(kk + 1) * 8192 + (co0 + m * 16 + q) * 32 + h * 8);
        }
#pragma unroll
        for (int nt = 0; nt < 4; ++nt)
#pragma unroll
            for (int m = 0; m < 2; ++m)
                acc[m][nt] = __builtin_amdgcn_mfma_f32_16x16x32_bf16(af[m], bf[nt], acc[m][nt], 0, 0, 0);
#pragma unroll
        for (int m = 0; m < 2; ++m) af[m] = afn[m];
    }

    // ---- t16 + t14 epilogue: in-register x+-3 via shuffles, coalesced stores ----
    float t14v[4];
#pragma unroll
    for (int nt = 0; nt < 4; ++nt) {
        int xx = nt * 16 + q;
        t14v[nt] = (xx < 56) ? t14l[xx] : 0.f;
    }
    const int srcm = (l & 48) | ((q + 13) & 15);
    const int srcp = (l & 48) | ((q + 3) & 15);
#pragma unroll
    for (int m = 0; m < 2; ++m) {
#pragma unroll
        for (int r = 0; r < 4; ++r) {
            int co = co0 + m * 16 + h * 4 + r;
            float wa = w16l[co * 3], wb = w16l[co * 3 + 1], wc = w16l[co * 3 + 2];
            float v[4], rm[4], rp[4];
#pragma unroll
            for (int nt = 0; nt < 4; ++nt) v[nt] = acc[m][nt][r];
#pragma unroll
            for (int nt = 0; nt < 4; ++nt) {
                rm[nt] = __shfl(v[nt], srcm, 64);
                rp[nt] = __shfl(v[nt], srcp, 64);
            }
            float* orow = out + ((size_t)(n * 256 + co) * 56 + y) * 56;
#pragma unroll
            for (int nt = 0; nt < 4; ++nt) {
                int xx = nt * 16 + q;
                float vm = (q >= 3) ? rm[nt] : (nt > 0 ? rm[nt - 1] : 0.f);
                float vp = (q < 13) ? rp[nt] : (nt < 3 ? rp[nt + 1] : 0.f);
                float s = v[nt] * wb + t14v[nt];
                s += (xx >= 3) ? vm * wa : 0.f;
                s += (xx <= 52) ? vp * wc : 0.f;
                if (xx < 56) orow[xx] = s;
            }
        }
    }
}

extern "C" void kernel_launch(void* const* d_in, const int* in_sizes, int n_in,
                              void* d_out, int out_size, void* d_ws, size_t ws_size,
                              hipStream_t stream) {
    const float* x   = (const float*)d_in[0];
    const float* w1  = (const float*)d_in[1];
    const float* p2w = (const float*)d_in[2];
    const float* w3  = (const float*)d_in[3];
    const float* w4  = (const float*)d_in[4];
    const float* w5  = (const float*)d_in[5];
    const float* w8  = (const float*)d_in[6];
    const float* w12 = (const float*)d_in[7];
    const float* w14 = (const float*)d_in[8];
    const float* w15 = (const float*)d_in[9];
    const float* w16 = (const float*)d_in[10];
    float* out = (float*)d_out;

    float* ws = (float*)d_ws;
    float* t1   = ws;                      // 3211264 f32
    char*  t8T  = (char*)(t1 + 3211264);   // 8,028,160 B
    float* t4   = t1 + 2 * 3211264;        // 100352 f32
    float* W34  = t4 + 100352;             // 288 f32
    __hip_bfloat16* Wfb = (__hip_bfloat16*)(W34 + 288);   // 172032 bf16
    __hip_bfloat16* w1b = Wfb + 172032;                   // 24576 bf16
    __hip_bfloat16* w8b = w1b + 24576;                    // 7168 bf16

    fuse_small<<<128, 256, 0, stream>>>(w3, w4, w1, w8, W34, w1b, w8b);
    k_t1f<<<1792, 256, 0, stream>>>(x, (const unsigned short*)w1b, t1);
    k_mid<<<2912, 256, 0, stream>>>(t1, p2w, w5, (const unsigned short*)w8b,
                                    w15, w12, W34, t8T, Wfb, t4);
    k_t15q<<<1792, 512, 0, stream>>>(t8T, (const unsigned short*)Wfb, w16, w14, t4, out);
}

// Round 14
// 158.209 us; speedup vs baseline: 1.4469x; 1.0134x over previous
//
#include <hip/hip_runtime.h>
#include <hip/hip_bf16.h>
#include <cstddef>

typedef __attribute__((ext_vector_type(8))) short s8v;
typedef __attribute__((ext_vector_type(4))) float f32x4;

// ---------------- L1: merged small repacks: W34 (288), w1b (24576), w8b (7168) ----------------
__global__ void fuse_small(const float* __restrict__ w3, const float* __restrict__ w4,
                           const float* __restrict__ w1, const float* __restrict__ w8,
                           float* __restrict__ W34, __hip_bfloat16* __restrict__ w1b,
                           __hip_bfloat16* __restrict__ w8b) {
    int idx = blockIdx.x * blockDim.x + threadIdx.x;
    if (idx < 288) {
        int ci = idx / 9, k1 = (idx / 3) % 3, k2 = idx % 3;
        float s = 0.f;
        for (int co = 0; co < 256; ++co)
            s += w3[(co * 32 + ci) * 3 + k1] * w4[co * 3 + k2];
        W34[idx] = s;
    }
    int i1 = idx - 512;
    if (i1 >= 0 && i1 < 24576) {
        int j = i1 & 7, co = (i1 >> 3) & 31, h = (i1 >> 8) & 3, c = (i1 >> 10) & 7, k = i1 >> 13;
        int ci = c * 32 + h * 8 + j;
        w1b[i1] = __float2bfloat16(w1[(co * 256 + ci) * 3 + k]);
    }
    int i2 = idx - 25600;
    if (i2 >= 0 && i2 < 7168) {
        int jj = i2 & 7, co = (i2 >> 3) & 31, h = (i2 >> 8) & 3, j = i2 >> 10;
        w8b[i2] = __float2bfloat16(w8[co * 224 + (h * 8 + jj) * 7 + j]);
    }
}

// ---------------- L2: t1 fused MFMA: conv 256->32, 3 w-taps dil 3 ----------------
__global__ __launch_bounds__(256) void k_t1f(const float* __restrict__ x,
                                             const unsigned short* __restrict__ w1b,
                                             float* __restrict__ t1) {
    __shared__ __align__(16) char lds[35840];
    const int t = threadIdx.x, b = blockIdx.x;
    const int n = b / 56, y = b % 56;
    const int w = t >> 6, l = t & 63, h = l >> 4, q = l & 15;
    const float* xr = x + (size_t)(n * 256) * 3136 + y * 56;

#pragma unroll
    for (int it = 0; it < 2; ++it) {
        int u = it * 256 + t;
        if (u < 448) {
            int pi = u >> 5, g = u & 31;
            int pos = (pi < 3) ? pi : (56 + pi);
            *reinterpret_cast<s8v*>(lds + pos * 512 + ((g ^ (pos & 15)) << 4)) = (s8v)0;
        }
    }
#pragma unroll 2
    for (int it = 0; it < 7; ++it) {
        int u = it * 256 + t;
        int c2 = u / 14, xq = u % 14;
        int ci = c2 * 2;
        float4 a = *(const float4*)(xr + (size_t)ci * 3136 + xq * 4);
        float4 bv = *(const float4*)(xr + (size_t)(ci + 1) * 3136 + xq * 4);
        int g = ci >> 3, lo = (ci & 7) * 2;
#pragma unroll
        for (int j = 0; j < 4; ++j) {
            int pos = xq * 4 + j + 3;
            __hip_bfloat16 b0 = __float2bfloat16(((const float*)&a)[j]);
            __hip_bfloat16 b1 = __float2bfloat16(((const float*)&bv)[j]);
            unsigned int wd = (unsigned int)(*(unsigned short*)&b0) |
                              ((unsigned int)(*(unsigned short*)&b1) << 16);
            *(unsigned int*)(lds + pos * 512 + ((g ^ (pos & 15)) << 4) + lo) = wd;
        }
    }
    __syncthreads();

    f32x4 acc[2];
    acc[0] = (f32x4)0.f;
    acc[1] = (f32x4)0.f;

    for (int c = 0; c < 8; ++c) {
        const int g = c * 4 + h;
#pragma unroll
        for (int k = 0; k < 3; ++k) {
            s8v af[2];
#pragma unroll
            for (int m = 0; m < 2; ++m)
                af[m] = *reinterpret_cast<const s8v*>(
                    w1b + (size_t)((((k * 8 + c) * 4 + h) * 32 + m * 16 + q) * 8));
            int pos = w * 16 + q + 3 * k;
            s8v bf = *reinterpret_cast<const s8v*>(lds + pos * 512 + ((g ^ (pos & 15)) << 4));
            acc[0] = __builtin_amdgcn_mfma_f32_16x16x32_bf16(af[0], bf, acc[0], 0, 0, 0);
            acc[1] = __builtin_amdgcn_mfma_f32_16x16x32_bf16(af[1], bf, acc[1], 0, 0, 0);
        }
    }

    int px = w * 16 + q;
    if (px < 56) {
#pragma unroll
        for (int m = 0; m < 2; ++m)
#pragma unroll
            for (int r = 0; r < 4; ++r)
                t1[((size_t)(n * 32 + m * 16 + h * 4 + r) * 56 + y) * 56 + px] = acc[m][r];
    }
}

// ---------------- L3: merged mid kernel ----------------
// blocks [0,1792): t5+t8 MFMA -> t8T (XCD-swizzled);
// [1792,2240): t4 (XCD-swizzled);  [2240,2912): fuse_w1215b (LDS-staged w12).
__global__ __launch_bounds__(256) void k_mid(const float* __restrict__ t1,
                                             const float* __restrict__ p2w,
                                             const float* __restrict__ w5,
                                             const unsigned short* __restrict__ w8b,
                                             const float* __restrict__ w15,
                                             const float* __restrict__ w12,
                                             const float* __restrict__ W34,
                                             char* __restrict__ t8T,
                                             __hip_bfloat16* __restrict__ Wfb,
                                             float* __restrict__ t4) {
    __shared__ __align__(16) char lds[14336];
    const int t = threadIdx.x, b = blockIdx.x;

    if (b >= 2240) {  // ---- fuse_w1215b role: LDS-staged w12, conflict-free reads ----
        int bb = b - 2240;           // 0..671
        int kk = bb >> 5;            // 0..20
        int oct = bb & 31;
        int dy = kk / 7, dx = kk - dy * 7;
        int ci = t & 31, col = t >> 5;
        int co = oct * 8 + col;
        float* w12s = (float*)lds;   // [16 m][32 ci][7 dx] = 3584 f32
        float s = 0.f;
        for (int c = 0; c < 16; ++c) {
            const float4* src = (const float4*)(w12 + c * 3584);
            for (int u = t; u < 896; u += 256)
                ((float4*)w12s)[u] = src[u];
            __syncthreads();
            int mbase = c * 16;
#pragma unroll
            for (int m = 0; m < 16; ++m) {
                float a = w15[co * 768 + (mbase + m) * 3 + dy];
                s += a * w12s[(m * 32 + ci) * 7 + dx];
            }
            __syncthreads();
        }
        Wfb[(size_t)kk * 8192 + co * 32 + ci] = __float2bfloat16(s);
        return;
    }
    if (b >= 1792) {  // ---- t4 role (XCD-swizzled: 448 = 8 x 56) ----
        int by = b - 1792;
        int v4 = (by & 7) * 56 + (by >> 3);
        int n = v4 / 14;
        int y = (v4 % 14) * 4 + (t >> 6);
        int px = t & 63;
        if (px >= 56) return;
        float acc = 0.f;
#pragma unroll 4
        for (int ci = 0; ci < 32; ++ci) {
#pragma unroll
            for (int k1 = 0; k1 < 3; ++k1) {
                int yy = y + 2 * k1 - 2;
                if (yy < 0 || yy >= 56) continue;
                const float* r = t1 + ((size_t)(n * 32 + ci) * 56 + yy) * 56;
#pragma unroll
                for (int k2 = 0; k2 < 3; ++k2) {
                    int xx = px + 3 * k2 - 3;
                    if (xx >= 0 && xx < 56)
                        acc += r[xx] * W34[ci * 9 + k1 * 3 + k2];
                }
            }
        }
        t4[(size_t)(n * 56 + y) * 56 + px] = acc;
        return;
    }

    // ---- t5+t8 MFMA role (XCD-swizzled: 1792 = 8 x 224) ----
    const int v = (b & 7) * 224 + (b >> 3);
    const int n = v / 56, y = v % 56;
    const int w = t >> 6, l = t & 63, h = l >> 4, q = l & 15;
    const float* t1b = t1 + (size_t)(n * 32) * 3136;
    char* rowbuf = lds + 4864;

    if (t < 80) {
        int ph = t >> 2, g = t & 3;
        int pos = (ph < 6) ? ph : (56 + ph);
        *reinterpret_cast<s8v*>(lds + pos * 64 + ((g ^ ((pos >> 1) & 3)) << 4)) = (s8v)0;
    }
    if (t >= 80 && t < 136) {
        int u = t - 80;
        int ph = u >> 2, g = u & 3;
        int pos = (ph < 3) ? ph : (56 + ph);
        *reinterpret_cast<s8v*>(rowbuf + pos * 64 + ((g ^ ((pos >> 1) & 3)) << 4)) = (s8v)0;
    }
#pragma unroll
    for (int it = 0; it < 2; ++it) {
        int u = it * 256 + t;
        if (u < 448) {
            int ci = u / 14, xq = u % 14;
            float sc = p2w[ci];
            float4 s = {0.f, 0.f, 0.f, 0.f};
#pragma unroll
            for (int k = 0; k < 3; ++k) {
                int yy = y + 3 * k - 3;
                if (yy < 0 || yy >= 56) continue;
                float wv = w5[ci * 3 + k] * sc;
                float4 vv = *(const float4*)(t1b + (size_t)ci * 3136 + yy * 56 + xq * 4);
                s.x += wv * vv.x; s.y += wv * vv.y; s.z += wv * vv.z; s.w += wv * vv.w;
            }
            int g = ci >> 3, lo = (ci & 7) * 2;
#pragma unroll
            for (int j = 0; j < 4; ++j) {
                int pos = xq * 4 + j + 6;
                __hip_bfloat16 bv = __float2bfloat16(((const float*)&s)[j]);
                *(unsigned short*)(lds + pos * 64 + ((g ^ ((pos >> 1) & 3)) << 4) + lo) =
                    *(unsigned short*)&bv;
            }
        }
    }
    __syncthreads();

    f32x4 acc[2];
    acc[0] = (f32x4)0.f; acc[1] = (f32x4)0.f;
#pragma unroll
    for (int j = 0; j < 7; ++j) {
        s8v af[2];
#pragma unroll
        for (int m = 0; m < 2; ++m)
            af[m] = *reinterpret_cast<const s8v*>(
                w8b + (size_t)(((j * 4 + h) * 32 + m * 16 + q) * 8));
        int pos = w * 16 + q + 2 * j;
        s8v bf = *reinterpret_cast<const s8v*>(lds + pos * 64 + ((h ^ ((pos >> 1) & 3)) << 4));
        acc[0] = __builtin_amdgcn_mfma_f32_16x16x32_bf16(af[0], bf, acc[0], 0, 0, 0);
        acc[1] = __builtin_amdgcn_mfma_f32_16x16x32_bf16(af[1], bf, acc[1], 0, 0, 0);
    }

    int xx = w * 16 + q;
    if (xx < 56) {
        int pos = xx + 3;
#pragma unroll
        for (int m = 0; m < 2; ++m) {
#pragma unroll
            for (int r = 0; r < 4; ++r) {
                int co = m * 16 + h * 4 + r;
                __hip_bfloat16 bv = __float2bfloat16(acc[m][r]);
                *(unsigned short*)(rowbuf + pos * 64 + (((co >> 3) ^ ((pos >> 1) & 3)) << 4) +
                                   (co & 7) * 2) = *(unsigned short*)&bv;
            }
        }
    }
    __syncthreads();
    char* rowo = t8T + (size_t)(n * 56 + y) * 4480;
    for (int u = t; u < 280; u += 256)
        *reinterpret_cast<s8v*>(rowo + u * 16) = *reinterpret_cast<const s8v*>(rowbuf + u * 16);
}

// ---------------- L4: t8T -> t15 -> t16 + (pool->t11->t14 from t4) -> out ----------------
// grid 1792 (XCD-swizzled), block 512 = 8 waves, 1 row/block, wave = 32-co slice.
// CHANGE vs k_t15q: invalid dy rows ZERO-FILLED in LDS -> K-loop is fully static
// (dy 0..2 x dx 0..6, #pragma unroll) so the compiler pipelines loads across kk.
__global__ __launch_bounds__(512) void k_t15r(const char* __restrict__ t8T,
                                              const unsigned short* __restrict__ Wfb,
                                              const float* __restrict__ w16,
                                              const float* __restrict__ w14,
                                              const float* __restrict__ t4,
                                              float* __restrict__ out) {
    __shared__ __align__(16) char lds[18816];
    float* Rr   = (float*)(lds + 13440);  // [5][64]
    float* Tt   = (float*)(lds + 14720);  // [3][64]
    float* t14l = (float*)(lds + 15488);  // [64]
    float* w16l = (float*)(lds + 15744);  // [768]
    const int t = threadIdx.x;
    const int b = blockIdx.x;
    const int vb = (b & 7) * 224 + (b >> 3);
    const int n = vb / 56, y = vb % 56;
    const int l = t & 63, h = l >> 4, q = l & 15;
    const int w = t >> 6;
    const int co0 = w * 32;
    const float* t4b = t4 + (size_t)n * 3136;

    // ---- stage 3 t8T rows y-2, y, y+2 (ridx = dy); zero-fill OOB rows ----
    for (int e = t; e < 840; e += 512) {
        int ridx = e / 280, u = e - ridx * 280;
        int yy = y + 2 * ridx - 2;
        s8v v = (s8v)0;
        if (yy >= 0 && yy < 56)
            v = *reinterpret_cast<const s8v*>(t8T + (size_t)(n * 56 + yy) * 4480 + u * 16);
        *reinterpret_cast<s8v*>(lds + ridx * 4480 + u * 16) = v;
    }
    // ---- w16 preload ----
    for (int e = t; e < 768; e += 512) w16l[e] = w16[e];
    // ---- pool pass 1: R rows yc = y-2 .. y+2 ----
    for (int e = t; e < 280; e += 512) {
        int ridx = e / 56, xx = e % 56;
        int yc = y - 2 + ridx;
        float rv = 0.f;
        if (yc >= 0 && yc < 56) {
            float mm = -3.4e38f;
#pragma unroll
            for (int i = 0; i < 7; ++i) {
                int yy = yc + 3 * i - 9;
                float v = (yy >= 0 && yy < 56) ? t4b[(size_t)yy * 56 + xx] : 0.f;
                mm = fmaxf(mm, v);
            }
            rv = fmaxf(mm, 0.f);
        }
        Rr[ridx * 64 + xx] = rv;
    }
    __syncthreads();
    // ---- pool pass 2: T (t11) rows yt = y-1 .. y+1 ----
    for (int e = t; e < 168; e += 512) {
        int ti = e / 56, px = e % 56;
        int yt = y - 1 + ti;
        float s = 0.f;
        if (yt >= 0 && yt < 56) {
#pragma unroll
            for (int dy = 0; dy < 3; ++dy) {
                int yr = yt + dy - 1;
                if (yr < 0 || yr >= 56) continue;
                int row = ti + dy;  // = yr - (y-2)
#pragma unroll
                for (int j = 0; j < 7; ++j) {
                    int xx = px + 3 * j - 9;
                    if (xx >= 0 && xx < 56) s += Rr[row * 64 + xx];
                }
            }
            s *= (1.f / 21.f);
        }
        Tt[ti * 64 + px] = s;
    }
    __syncthreads();
    // ---- pool pass 3: t14 row y ----
    if (t < 56) {
        int px = t;
        float s = 0.f;
#pragma unroll
        for (int dy = 0; dy < 3; ++dy) {
            int yy = y + dy - 1;
            if (yy < 0 || yy >= 56) continue;
#pragma unroll
            for (int dx = 0; dx < 3; ++dx) {
                int xx = px + dx - 1;
                if (xx < 0 || xx >= 56) continue;
                s += Tt[dy * 64 + xx] * w14[dy * 3 + dx];
            }
        }
        t14l[px] = s;
    }
    __syncthreads();

    f32x4 acc[2][4];
#pragma unroll
    for (int m = 0; m < 2; ++m)
#pragma unroll
        for (int nt = 0; nt < 4; ++nt)
            acc[m][nt] = (f32x4)0.f;

    // ---- fully static unrolled K-loop: 21 kk, loads pipelined by compiler ----
#pragma unroll
    for (int dy = 0; dy < 3; ++dy) {
        const char* bbase = lds + dy * 4480;
#pragma unroll
        for (int dx = 0; dx < 7; ++dx) {
            const int kk = dy * 7 + dx;
            s8v af[2];
#pragma unroll
            for (int m = 0; m < 2; ++m)
                af[m] = *reinterpret_cast<const s8v*>(
                    Wfb + (size_t)kk * 8192 + (co0 + m * 16 + q) * 32 + h * 8);
            s8v bf[4];
#pragma unroll
            for (int nt = 0; nt < 4; ++nt) {
                int xp = nt * 16 + q + dx;
                bf[nt] = *reinterpret_cast<const s8v*>(
                    bbase + xp * 64 + ((h ^ ((xp >> 1) & 3)) << 4));
            }
#pragma unroll
            for (int nt = 0; nt < 4; ++nt)
#pragma unroll
                for (int m = 0; m < 2; ++m)
                    acc[m][nt] =
                        __builtin_amdgcn_mfma_f32_16x16x32_bf16(af[m], bf[nt], acc[m][nt], 0, 0, 0);
        }
    }

    // ---- t16 + t14 epilogue: in-register x+-3 via shuffles, coalesced stores ----
    float t14v[4];
#pragma unroll
    for (int nt = 0; nt < 4; ++nt) {
        int xx = nt * 16 + q;
        t14v[nt] = (xx < 56) ? t14l[xx] : 0.f;
    }
    const int srcm = (l & 48) | ((q + 13) & 15);
    const int srcp = (l & 48) | ((q + 3) & 15);
#pragma unroll
    for (int m = 0; m < 2; ++m) {
#pragma unroll
        for (int r = 0; r < 4; ++r) {
            int co = co0 + m * 16 + h * 4 + r;
            float wa = w16l[co * 3], wb = w16l[co * 3 + 1], wc = w16l[co * 3 + 2];
            float v[4], rm[4], rp[4];
#pragma unroll
            for (int nt = 0; nt < 4; ++nt) v[nt] = acc[m][nt][r];
#pragma unroll
            for (int nt = 0; nt < 4; ++nt) {
                rm[nt] = __shfl(v[nt], srcm, 64);
                rp[nt] = __shfl(v[nt], srcp, 64);
            }
            float* orow = out + ((size_t)(n * 256 + co) * 56 + y) * 56;
#pragma unroll
            for (int nt = 0; nt < 4; ++nt) {
                int xx = nt * 16 + q;
                float vm = (q >= 3) ? rm[nt] : (nt > 0 ? rm[nt - 1] : 0.f);
                float vp = (q < 13) ? rp[nt] : (nt < 3 ? rp[nt + 1] : 0.f);
                float s = v[nt] * wb + t14v[nt];
                s += (xx >= 3) ? vm * wa : 0.f;
                s += (xx <= 52) ? vp * wc : 0.f;
                if (xx < 56) orow[xx] = s;
            }
        }
    }
}

extern "C" void kernel_launch(void* const* d_in, const int* in_sizes, int n_in,
                              void* d_out, int out_size, void* d_ws, size_t ws_size,
                              hipStream_t stream) {
    const float* x   = (const float*)d_in[0];
    const float* w1  = (const float*)d_in[1];
    const float* p2w = (const float*)d_in[2];
    const float* w3  = (const float*)d_in[3];
    const float* w4  = (const float*)d_in[4];
    const float* w5  = (const float*)d_in[5];
    const float* w8  = (const float*)d_in[6];
    const float* w12 = (const float*)d_in[7];
    const float* w14 = (const float*)d_in[8];
    const float* w15 = (const float*)d_in[9];
    const float* w16 = (const float*)d_in[10];
    float* out = (float*)d_out;

    float* ws = (float*)d_ws;
    float* t1   = ws;                      // 3211264 f32
    char*  t8T  = (char*)(t1 + 3211264);   // 8,028,160 B
    float* t4   = t1 + 2 * 3211264;        // 100352 f32
    float* W34  = t4 + 100352;             // 288 f32
    __hip_bfloat16* Wfb = (__hip_bfloat16*)(W34 + 288);   // 172032 bf16
    __hip_bfloat16* w1b = Wfb + 172032;                   // 24576 bf16
    __hip_bfloat16* w8b = w1b + 24576;                    // 7168 bf16

    fuse_small<<<128, 256, 0, stream>>>(w3, w4, w1, w8, W34, w1b, w8b);
    k_t1f<<<1792, 256, 0, stream>>>(x, (const unsigned short*)w1b, t1);
    k_mid<<<2912, 256, 0, stream>>>(t1, p2w, w5, (const unsigned short*)w8b,
                                    w15, w12, W34, t8T, Wfb, t4);
    k_t15r<<<1792, 512, 0, stream>>>(t8T, (const unsigned short*)Wfb, w16, w14, t4, out);
}